// Round 1
// baseline (30385.303 us; speedup 1.0000x reference)
//
#include <hip/hip_runtime.h>

#define Bb 8
#define Ss 4096
#define Dd 512
#define Hh 1024
#define CSc 64
#define NCn 64
#define MROW 512  // Bb*CSc
#define GRIDB 256 // persistent scan grid (1 block/CU)

typedef unsigned short ushort_t;
typedef short s8v __attribute__((ext_vector_type(8)));          // 8 bf16 for MFMA A/B
typedef unsigned short u8v __attribute__((ext_vector_type(8))); // raw 8x bf16 storage
typedef float f4v __attribute__((ext_vector_type(4)));          // MFMA C/D

enum { PH_PROJ=0, PH_H1, PH_PRED, PH_D1, PH_UPD1, PH_UPD2, PH_H1Q, PH_R, PH_OUTC };

struct Ptrs {
  const float *x, *Wk, *Wv, *Wq, *Wout, *W1, *W2;
  ushort_t *kbuf, *vbuf, *qbuf, *rbuf;
  ushort_t *h1, *a1, *d1b, *d2b;
  float *Wd1, *M1, *Wd2, *M2;
  float *gates;
  float *out;
};

__device__ __forceinline__ float b2f(ushort_t u){
  union { unsigned int i; float f; } c; c.i = ((unsigned int)u) << 16; return c.f;
}
__device__ __forceinline__ ushort_t f2b(float f){
  union { float f; unsigned int i; } c; c.f = f;
  unsigned int i = c.i;
  i += 0x7fffu + ((i >> 16) & 1u);   // RTNE
  return (ushort_t)(i >> 16);
}
__device__ __forceinline__ float sig_(float v){ return 1.0f/(1.0f+__expf(-v)); }
__device__ __forceinline__ float silu_(float v){ return v*sig_(v); }
__device__ __forceinline__ float dsilu_(float v){ float s=sig_(v); return s*(1.0f + v*(1.0f-s)); }
__device__ __forceinline__ float clip1_(float v){ return fminf(fmaxf(v,-1.0f),1.0f); }
// row index m=(b,c) -> flat [b*S + nc*64 + c]*D + d
__device__ __forceinline__ size_t cidx(int m, int d, int nc){
  return ((size_t)((m>>6)*Ss) + nc*CSc + (m&63))*Dd + d;
}

// ================= MFMA bf16 GEMM body: 64x64 tile, 4 waves 2x2, BK=32 ==========
// LDS buffers passed in (persistent kernel shares one pair across all phases).
template<int PHASE, int KD>
__device__ __forceinline__ void gemm_body(const Ptrs& p, int nc, int bx, int by,
                                          const float* Wp, ushort_t* Cp,
                                          ushort_t* As, ushort_t* Bs) {
  constexpr int BK=32, STR=40;   // STR shorts = 80B, 16B-aligned rows
  const int tid = threadIdx.x;
  const int m0 = bx*64, n0 = by*64;
  const int wave = tid>>6, lane = tid&63;
  const int wm = wave&1, wn = wave>>1;
  const int quad = lane>>4, l16 = lane&15;

  f4v zz = {0.f,0.f,0.f,0.f};
  f4v acc[2][2];
  acc[0][0]=zz; acc[0][1]=zz; acc[1][0]=zz; acc[1][1]=zz;

  for (int k0=0; k0<KD; k0+=BK) {
    // ---------------- stage A (As[mm][kk], bf16) ----------------
    if constexpr (PHASE==PH_UPD1 || PHASE==PH_UPD2) {
      // A[m][k] = src[k][m] (transposed): read contiguous m, scatter to LDS
      int kk = tid>>3, mm0 = (tid&7)*8;
      const ushort_t* src; int stride;
      if constexpr (PHASE==PH_UPD1){ src = p.d1b; stride = Hh; }
      else                         { src = p.d2b; stride = Dd; }
      u8v v = *(const u8v*)&src[(size_t)(k0+kk)*stride + m0+mm0];
      #pragma unroll
      for (int j=0;j<8;j++) As[(mm0+j)*STR + kk] = v[j];
    } else if constexpr (PHASE==PH_PROJ) {
      int mm = tid>>2, kk0 = (tid&3)*8;
      const float* s = &p.x[(size_t)(m0+mm)*Dd + (k0+kk0)];
      float4 f0 = *(const float4*)s, f1 = *(const float4*)(s+4);
      u8v o; o[0]=f2b(f0.x);o[1]=f2b(f0.y);o[2]=f2b(f0.z);o[3]=f2b(f0.w);
             o[4]=f2b(f1.x);o[5]=f2b(f1.y);o[6]=f2b(f1.z);o[7]=f2b(f1.w);
      *(u8v*)&As[mm*STR + kk0] = o;
    } else {
      int mm = tid>>2, kk0 = (tid&3)*8;
      int m = m0+mm, k = k0+kk0;
      const ushort_t* s;
      if constexpr (PHASE==PH_H1)        s = &p.kbuf[cidx(m,k,nc)];
      else if constexpr (PHASE==PH_H1Q)  s = &p.qbuf[cidx(m,k,nc)];
      else if constexpr (PHASE==PH_PRED) s = &p.a1[(size_t)m*Hh+k];
      else if constexpr (PHASE==PH_R)    s = &p.d1b[(size_t)m*Hh+k];
      else if constexpr (PHASE==PH_D1)   s = &p.d2b[(size_t)m*Dd+k];
      else /*PH_OUTC*/                   s = &p.rbuf[(size_t)m*Dd+k];
      *(u8v*)&As[mm*STR + kk0] = *(const u8v*)s;
    }
    // ---------------- stage B (Bs[nn][kk] = B[k][n] with n-major rows) ----------
    if constexpr (PHASE==PH_D1) {
      // B[n=h][k=d] = E2[d][h]: read 8 consecutive h for fixed d, scatter
      int kk = tid>>3, nn0 = (tid&7)*8;
      size_t off = (size_t)(k0+kk)*Hh + (n0+nn0);
      float4 a0 = *(const float4*)&p.W2[off],  a1_ = *(const float4*)&p.W2[off+4];
      float4 b0 = *(const float4*)&p.Wd2[off], b1_ = *(const float4*)&p.Wd2[off+4];
      Bs[(nn0+0)*STR+kk]=f2b(a0.x+b0.x); Bs[(nn0+1)*STR+kk]=f2b(a0.y+b0.y);
      Bs[(nn0+2)*STR+kk]=f2b(a0.z+b0.z); Bs[(nn0+3)*STR+kk]=f2b(a0.w+b0.w);
      Bs[(nn0+4)*STR+kk]=f2b(a1_.x+b1_.x); Bs[(nn0+5)*STR+kk]=f2b(a1_.y+b1_.y);
      Bs[(nn0+6)*STR+kk]=f2b(a1_.z+b1_.z); Bs[(nn0+7)*STR+kk]=f2b(a1_.w+b1_.w);
    } else if constexpr (PHASE==PH_UPD1) {
      // B[n=d][k=token] = kch[token][d]
      int kk = tid>>3, nn0 = (tid&7)*8;
      u8v v = *(const u8v*)&p.kbuf[cidx(k0+kk, n0+nn0, nc)];
      #pragma unroll
      for (int j=0;j<8;j++) Bs[(nn0+j)*STR + kk] = v[j];
    } else if constexpr (PHASE==PH_UPD2) {
      // B[n=h][k=token] = a1[token][h]
      int kk = tid>>3, nn0 = (tid&7)*8;
      u8v v = *(const u8v*)&p.a1[(size_t)(k0+kk)*Hh + (n0+nn0)];
      #pragma unroll
      for (int j=0;j<8;j++) Bs[(nn0+j)*STR + kk] = v[j];
    } else {
      // row-major fp32 B[n][k] (weights, optionally + Wd)
      int nn = tid>>2, kk0 = (tid&3)*8;
      int n = n0+nn, k = k0+kk0;
      const float *s1, *s2 = nullptr;
      if constexpr (PHASE==PH_PROJ)      { s1 = &Wp[(size_t)n*Dd+k]; }
      else if constexpr (PHASE==PH_OUTC) { s1 = &p.Wout[(size_t)n*Dd+k]; }
      else if constexpr (PHASE==PH_H1 || PHASE==PH_H1Q)
           { s1 = &p.W1[(size_t)n*Dd+k]; s2 = &p.Wd1[(size_t)n*Dd+k]; }
      else /*PRED,R*/
           { s1 = &p.W2[(size_t)n*Hh+k]; s2 = &p.Wd2[(size_t)n*Hh+k]; }
      float4 f0 = *(const float4*)s1, f1 = *(const float4*)(s1+4);
      if (s2) {
        float4 g0 = *(const float4*)s2, g1 = *(const float4*)(s2+4);
        f0.x+=g0.x; f0.y+=g0.y; f0.z+=g0.z; f0.w+=g0.w;
        f1.x+=g1.x; f1.y+=g1.y; f1.z+=g1.z; f1.w+=g1.w;
      }
      u8v o; o[0]=f2b(f0.x);o[1]=f2b(f0.y);o[2]=f2b(f0.z);o[3]=f2b(f0.w);
             o[4]=f2b(f1.x);o[5]=f2b(f1.y);o[6]=f2b(f1.z);o[7]=f2b(f1.w);
      *(u8v*)&Bs[nn*STR + kk0] = o;
    }
    __syncthreads();
    // ---------------- MFMA ----------------
    s8v a0 = *(const s8v*)&As[(wm*32 +  0 + l16)*STR + quad*8];
    s8v a1f= *(const s8v*)&As[(wm*32 + 16 + l16)*STR + quad*8];
    s8v b0 = *(const s8v*)&Bs[(wn*32 +  0 + l16)*STR + quad*8];
    s8v b1f= *(const s8v*)&Bs[(wn*32 + 16 + l16)*STR + quad*8];
    acc[0][0] = __builtin_amdgcn_mfma_f32_16x16x32_bf16(a0,  b0,  acc[0][0], 0,0,0);
    acc[0][1] = __builtin_amdgcn_mfma_f32_16x16x32_bf16(a0,  b1f, acc[0][1], 0,0,0);
    acc[1][0] = __builtin_amdgcn_mfma_f32_16x16x32_bf16(a1f, b0,  acc[1][0], 0,0,0);
    acc[1][1] = __builtin_amdgcn_mfma_f32_16x16x32_bf16(a1f, b1f, acc[1][1], 0,0,0);
    __syncthreads();
  }

  // ---------------- epilogue: D row = quad*4+r, col = l16 ----------------
  float al=0.f, lr=0.f, et=0.f;
  if constexpr (PHASE==PH_UPD1 || PHASE==PH_UPD2) {
    al = p.gates[nc]; lr = p.gates[NCn+nc]; et = p.gates[2*NCn+nc];
  }
  #pragma unroll
  for (int mf=0; mf<2; mf++) {
    #pragma unroll
    for (int nf=0; nf<2; nf++) {
      #pragma unroll
      for (int r=0; r<4; r++) {
        int m = m0 + wm*32 + mf*16 + quad*4 + r;
        int n = n0 + wn*32 + nf*16 + l16;
        float v = acc[mf][nf][r];
        if constexpr (PHASE==PH_PROJ)      Cp[(size_t)m*Dd+n] = f2b(v);
        else if constexpr (PHASE==PH_OUTC) p.out[cidx(m,n,nc)] = v;
        else if constexpr (PHASE==PH_H1) {
          p.h1[(size_t)m*Hh+n] = f2b(v);
          p.a1[(size_t)m*Hh+n] = f2b(silu_(v));
        }
        else if constexpr (PHASE==PH_H1Q)  p.d1b[(size_t)m*Hh+n] = f2b(silu_(v));
        else if constexpr (PHASE==PH_PRED) {
          float e = clip1_(v - b2f(p.vbuf[cidx(m,n,nc)]));
          p.d2b[(size_t)m*Dd+n] = f2b(0.03125f*e);   // scale = 2/CS
        }
        else if constexpr (PHASE==PH_R)    p.rbuf[(size_t)m*Dd+n] = f2b(v);
        else if constexpr (PHASE==PH_D1)
          p.d1b[(size_t)m*Hh+n] = f2b(v * dsilu_(b2f(p.h1[(size_t)m*Hh+n])));
        else if constexpr (PHASE==PH_UPD1) {
          float g = clip1_(v);
          size_t idx = (size_t)m*Dd+n;
          float m1 = et*p.M1[idx] - lr*g;
          p.M1[idx] = m1;
          p.Wd1[idx] = (1.0f-al)*p.Wd1[idx] + m1;
        }
        else if constexpr (PHASE==PH_UPD2) {
          float g = clip1_(v);
          size_t idx = (size_t)m*Hh+n;
          float m2 = et*p.M2[idx] - lr*g;
          p.M2[idx] = m2;
          p.Wd2[idx] = (1.0f-al)*p.Wd2[idx] + m2;
        }
      }
    }
  }
}

// ---------------- projections (massively parallel, stays a normal launch) -------
__global__ __launch_bounds__(256) void gk_proj(Ptrs p){
  __shared__ ushort_t As[64*40];
  __shared__ ushort_t Bs[64*40];
  const float* Wp = blockIdx.z==0 ? p.Wk : (blockIdx.z==1 ? p.Wv : p.Wq);
  ushort_t*    Cp = blockIdx.z==0 ? p.kbuf : (blockIdx.z==1 ? p.vbuf : p.qbuf);
  gemm_body<PH_PROJ,Dd>(p, 0, blockIdx.x, blockIdx.y, Wp, Cp, As, Bs);
}

// ---------------- device-scope grid barrier for the persistent scan -------------
// bar[0] = arrive counter, bar[1] = generation. Zeroed host-side each launch.
__device__ __forceinline__ void gridbar(unsigned* bar){
  __threadfence();            // flush this thread's writes device-wide (agent fence)
  __syncthreads();
  if (threadIdx.x==0){
    unsigned gen  = __hip_atomic_load(&bar[1], __ATOMIC_RELAXED, __HIP_MEMORY_SCOPE_AGENT);
    unsigned prev = __hip_atomic_fetch_add(&bar[0], 1u, __ATOMIC_ACQ_REL, __HIP_MEMORY_SCOPE_AGENT);
    if (prev == (unsigned)(GRIDB-1)){
      __hip_atomic_store(&bar[0], 0u,     __ATOMIC_RELAXED, __HIP_MEMORY_SCOPE_AGENT);
      __hip_atomic_store(&bar[1], gen+1u, __ATOMIC_RELEASE, __HIP_MEMORY_SCOPE_AGENT);
    } else {
      while (__hip_atomic_load(&bar[1], __ATOMIC_ACQUIRE, __HIP_MEMORY_SCOPE_AGENT) == gen)
        __builtin_amdgcn_s_sleep(2);
    }
  }
  __syncthreads();
  __threadfence();            // invalidate stale cached lines before epoch reads
}

// ---------------- persistent fused scan: 4 epochs/chunk, pipelined across chunks
// Epoch A: UPD1(nc)[128] + UPD2(nc)[128]
// Epoch B: H1Q(nc)[128] + H1(nc+1)[128]
// Epoch C: R(nc)[64]    + PRED(nc+1)[64]
// Epoch D: OUTC(nc)[64] + D1(nc+1)[128]
// (D1(nc+1) reads Wd2 one epoch BEFORE UPD2(nc+1) writes it -> race-free, ref-exact)
__global__ __launch_bounds__(256) void scan_k(Ptrs p, unsigned* bar){
  __shared__ ushort_t As[64*40];
  __shared__ ushort_t Bs[64*40];
  const int bid = blockIdx.x;

  // prologue: chunk 0 head of the dependency chain
  if (bid < 128) gemm_body<PH_H1,  Dd>(p, 0, bid>>4, bid&15, nullptr,nullptr, As,Bs);
  gridbar(bar);
  if (bid < 64)  gemm_body<PH_PRED,Hh>(p, 0, bid>>3, bid&7,  nullptr,nullptr, As,Bs);
  gridbar(bar);
  if (bid < 128) gemm_body<PH_D1,  Dd>(p, 0, bid>>4, bid&15, nullptr,nullptr, As,Bs);
  gridbar(bar);

  for (int nc = 0; nc < NCn; ++nc) {
    const bool more = (nc+1 < NCn);
    // ---- Epoch A: weight updates (disjoint outputs Wd1/M1 vs Wd2/M2) ----
    if (bid < 128) gemm_body<PH_UPD1,MROW>(p, nc, bid>>3, bid&7, nullptr,nullptr, As,Bs);
    else           gemm_body<PH_UPD2,MROW>(p, nc, (bid-128)>>4, (bid-128)&15, nullptr,nullptr, As,Bs);
    gridbar(bar);
    // ---- Epoch B: both consumers of Wd1_new ----
    if (bid < 128)      gemm_body<PH_H1Q,Dd>(p, nc,   bid>>4, bid&15, nullptr,nullptr, As,Bs);
    else if (more)      gemm_body<PH_H1, Dd>(p, nc+1, (bid-128)>>4, (bid-128)&15, nullptr,nullptr, As,Bs);
    gridbar(bar);
    // ---- Epoch C: both consumers of Wd2_new ----
    if (bid < 64)              gemm_body<PH_R,   Hh>(p, nc,   bid>>3, bid&7, nullptr,nullptr, As,Bs);
    else if (bid < 128 && more) gemm_body<PH_PRED,Hh>(p, nc+1, (bid-64)>>3, (bid-64)&7, nullptr,nullptr, As,Bs);
    gridbar(bar);
    // ---- Epoch D: output proj of nc + backward of nc+1 ----
    if (bid < 64)              gemm_body<PH_OUTC,Dd>(p, nc,   bid>>3, bid&7, nullptr,nullptr, As,Bs);
    else if (bid < 192 && more) gemm_body<PH_D1, Dd>(p, nc+1, (bid-64)>>4, (bid-64)&15, nullptr,nullptr, As,Bs);
    gridbar(bar);
  }
}

// ---------------- zero helper ----------------------------------------------------
__global__ __launch_bounds__(256)
void zero_k(float* __restrict__ ptr, int n){
  int i = blockIdx.x*256 + threadIdx.x;
  int stride = gridDim.x*256;
  for (; i < n; i += stride) ptr[i] = 0.0f;
}

// ---------------- halo save (last 3 rows of each chunk, pre-conv) ----------------
__global__ void halo_k(const ushort_t* __restrict__ kbuf, const ushort_t* __restrict__ vbuf,
                       const ushort_t* __restrict__ qbuf, ushort_t* __restrict__ halo){
  int bid = blockIdx.x;
  int t = bid / (NCn*Bb);
  int rem = bid % (NCn*Bb);
  int nc = rem / Bb, b = rem % Bb;
  const ushort_t* src = (t==0)?kbuf:((t==1)?vbuf:qbuf);
  ushort_t* dst = halo + (((size_t)t*NCn + nc)*Bb + b)*3*Dd;
  for (int e = threadIdx.x; e < 3*Dd; e += 256){
    int j = e / Dd, d = e % Dd;
    int s = nc*CSc + 61 + j;
    dst[e] = src[((size_t)b*Ss + s)*Dd + d];
  }
}

// ---------------- in-place causal depthwise conv (K=4) ---------------------------
__global__ void conv_k(ushort_t* __restrict__ kbuf, ushort_t* __restrict__ vbuf, ushort_t* __restrict__ qbuf,
                       const float* __restrict__ ckw, const float* __restrict__ ckb,
                       const float* __restrict__ cvw, const float* __restrict__ cvb,
                       const float* __restrict__ cqw, const float* __restrict__ cqb,
                       const ushort_t* __restrict__ halo){
  int bid = blockIdx.x;
  int t = bid / (NCn*Bb);
  int rem = bid % (NCn*Bb);
  int nc = rem / Bb, b = rem % Bb;
  ushort_t* buf = (t==0)?kbuf:((t==1)?vbuf:qbuf);
  const float* cw = (t==0)?ckw:((t==1)?cvw:cqw);
  const float* cb = (t==0)?ckb:((t==1)?cvb:cqb);
  const ushort_t* hl = halo + (((size_t)t*NCn + (nc>0?nc-1:0))*Bb + b)*3*Dd;
  for (int rep=0; rep<2; ++rep){
    int d = threadIdx.x + rep*256;
    float w0 = cw[d*4+0], w1 = cw[d*4+1], w2 = cw[d*4+2], w3 = cw[d*4+3];
    float bias = cb[d];
    float p1, p2, p3;
    if (nc == 0) { p1=p2=p3=0.0f; }
    else { p1 = b2f(hl[2*Dd+d]); p2 = b2f(hl[1*Dd+d]); p3 = b2f(hl[0*Dd+d]); }
    ushort_t* row = buf + ((size_t)b*Ss + nc*CSc)*Dd + d;
    for (int c=0;c<CSc;++c){
      float cur = b2f(row[(size_t)c*Dd]);
      float o = w3*cur + w2*p1 + w1*p2 + w0*p3 + bias;
      p3 = p2; p2 = p1; p1 = cur;
      row[(size_t)c*Dd] = f2b(o);
    }
  }
}

// ---------------- per-chunk scalar gates -----------------------------------------
__global__ __launch_bounds__(256)
void gates_k(const float* __restrict__ x,
             const float* __restrict__ wd, const float* __restrict__ bd,
             const float* __restrict__ wl, const float* __restrict__ bl,
             const float* __restrict__ we, const float* __restrict__ be,
             float* __restrict__ gates){
  int nc = blockIdx.x;
  int wave = threadIdx.x >> 6, lane = threadIdx.x & 63;
  __shared__ float red[4][3];
  float accA=0.f, accL=0.f, accE=0.f;
  float bdv = bd[0], blv = bl[0], bev = be[0];
  for (int pi = wave; pi < Bb*CSc; pi += 4) {
    int b = pi / CSc, c = pi % CSc;
    const float* xr = x + ((size_t)b*Ss + nc*CSc + c)*Dd + lane*8;
    float da=0.f, dl=0.f, de=0.f;
    #pragma unroll
    for (int u=0;u<8;++u){
      float xv = xr[u];
      int d = lane*8+u;
      da += xv*wd[d]; dl += xv*wl[d]; de += xv*we[d];
    }
    #pragma unroll
    for (int off=32; off; off>>=1){
      da += __shfl_down(da, off);
      dl += __shfl_down(dl, off);
      de += __shfl_down(de, off);
    }
    if (lane==0){
      accA += sig_(da + bdv);
      accL += sig_(dl + blv);
      accE += sig_(de + bev);
    }
  }
  if (lane==0){ red[wave][0]=accA; red[wave][1]=accL; red[wave][2]=accE; }
  __syncthreads();
  if (threadIdx.x==0){
    float a=0.f,l=0.f,e=0.f;
    for (int w=0;w<4;w++){ a+=red[w][0]; l+=red[w][1]; e+=red[w][2]; }
    gates[nc]        = a*(1.0f/512.0f);
    gates[NCn+nc]    = l*(1.0f/512.0f);
    gates[2*NCn+nc]  = e*(1.0f/512.0f);
  }
}

extern "C" void kernel_launch(void* const* d_in, const int* in_sizes, int n_in,
                              void* d_out, int out_size, void* d_ws, size_t ws_size,
                              hipStream_t stream) {
  (void)in_sizes; (void)n_in; (void)out_size;
  const float* x       = (const float*)d_in[0];
  const float* Wk      = (const float*)d_in[1];
  const float* Wv      = (const float*)d_in[2];
  const float* Wq      = (const float*)d_in[3];
  const float* Wout    = (const float*)d_in[4];
  const float* ckw     = (const float*)d_in[5];
  const float* ckb     = (const float*)d_in[6];
  const float* cvw     = (const float*)d_in[7];
  const float* cvb     = (const float*)d_in[8];
  const float* cqw     = (const float*)d_in[9];
  const float* cqb     = (const float*)d_in[10];
  const float* w_decay = (const float*)d_in[11];
  const float* b_decay = (const float*)d_in[12];
  const float* w_lr    = (const float*)d_in[13];
  const float* b_lr    = (const float*)d_in[14];
  const float* w_eta   = (const float*)d_in[15];
  const float* b_eta   = (const float*)d_in[16];
  const float* W1      = (const float*)d_in[17];
  const float* W2      = (const float*)d_in[18];

  // ---- workspace carve: fp32 state first, then bf16 buffers ----
  char* base = (char*)d_ws;
  size_t off = 0;
  auto alloc_f = [&](size_t n)->float*   { float* r=(float*)(base+off);   off += n*4; return r; };
  auto alloc_b = [&](size_t n)->ushort_t*{ ushort_t* r=(ushort_t*)(base+off); off += n*2; off=(off+15)&~15ull; return r; };

  float* Wd1  = alloc_f((size_t)Hh*Dd);
  float* M1   = alloc_f((size_t)Hh*Dd);
  float* Wd2  = alloc_f((size_t)Dd*Hh);
  float* M2   = alloc_f((size_t)Dd*Hh);
  float* gates= alloc_f(3*NCn + 4);
  float* barf = alloc_f(4);               // grid-barrier state (zeroed per launch)

  const size_t BSD = (size_t)Bb*Ss*Dd;
  ushort_t* kbuf = alloc_b(BSD);
  ushort_t* vbuf = alloc_b(BSD);
  ushort_t* qbuf = alloc_b(BSD);
  ushort_t* halo = alloc_b((size_t)3*NCn*Bb*3*Dd);
  ushort_t* h1   = alloc_b((size_t)MROW*Hh);
  ushort_t* a1   = alloc_b((size_t)MROW*Hh);
  ushort_t* d1b  = alloc_b((size_t)MROW*Hh);
  ushort_t* d2b  = alloc_b((size_t)MROW*Dd);
  ushort_t* rbuf = alloc_b((size_t)MROW*Dd);

  if (ws_size < off) return;  // clean fail instead of fault

  // zero scan state (Wd1,M1,Wd2,M2 contiguous) + barrier words
  zero_k<<<512, 256, 0, stream>>>(Wd1, 4*Hh*Dd);
  zero_k<<<1, 64, 0, stream>>>(barf, 4);

  Ptrs p;
  p.x=x; p.Wk=Wk; p.Wv=Wv; p.Wq=Wq; p.Wout=Wout; p.W1=W1; p.W2=W2;
  p.kbuf=kbuf; p.vbuf=vbuf; p.qbuf=qbuf; p.rbuf=rbuf;
  p.h1=h1; p.a1=a1; p.d1b=d1b; p.d2b=d2b;
  p.Wd1=Wd1; p.M1=M1; p.Wd2=Wd2; p.M2=M2;
  p.gates=gates; p.out=(float*)d_out;

  // projections: k/v/q = bf16(x) @ bf16(W^T)
  gk_proj<<<dim3(Bb*Ss/64, Dd/64, 3), 256, 0, stream>>>(p);
  halo_k<<<3*NCn*Bb, 256, 0, stream>>>(kbuf, vbuf, qbuf, halo);
  conv_k<<<3*NCn*Bb, 256, 0, stream>>>(kbuf, vbuf, qbuf, ckw, ckb, cvw, cvb, cqw, cqb, halo);
  gates_k<<<NCn, 256, 0, stream>>>(x, w_decay, b_decay, w_lr, b_lr, w_eta, b_eta, gates);

  // fused persistent chunk scan: 1 launch, 259 grid barriers, 4 epochs/chunk
  scan_k<<<GRIDB, 256, 0, stream>>>(p, (unsigned*)barf);
}

// Round 2
// 10159.792 us; speedup vs baseline: 2.9907x; 2.9907x over previous
//
#include <hip/hip_runtime.h>

#define Bb 8
#define Ss 4096
#define Dd 512
#define Hh 1024
#define CSc 64
#define NCn 64
#define MROW 512  // Bb*CSc
#define GRIDB 256 // persistent scan grid (1 block/CU)

typedef unsigned short ushort_t;
typedef short s8v __attribute__((ext_vector_type(8)));          // 8 bf16 for MFMA A/B
typedef unsigned short u8v __attribute__((ext_vector_type(8))); // raw 8x bf16 storage
typedef float f4v __attribute__((ext_vector_type(4)));          // MFMA C/D
typedef float f4x __attribute__((ext_vector_type(4)));          // 16B float vector (volatile-safe)

enum { PH_PROJ=0, PH_H1, PH_PRED, PH_D1, PH_UPD1, PH_UPD2, PH_H1Q, PH_R, PH_OUTC };

struct Ptrs {
  const float *x, *Wk, *Wv, *Wq, *Wout, *W1, *W2;
  ushort_t *kbuf, *vbuf, *qbuf, *rbuf;
  ushort_t *h1, *a1, *d1b, *d2b;
  float *Wd1, *M1, *Wd2, *M2;
  float *gates;
  float *out;
};

__device__ __forceinline__ float b2f(ushort_t u){
  union { unsigned int i; float f; } c; c.i = ((unsigned int)u) << 16; return c.f;
}
__device__ __forceinline__ ushort_t f2b(float f){
  union { float f; unsigned int i; } c; c.f = f;
  unsigned int i = c.i;
  i += 0x7fffu + ((i >> 16) & 1u);   // RTNE
  return (ushort_t)(i >> 16);
}
__device__ __forceinline__ float sig_(float v){ return 1.0f/(1.0f+__expf(-v)); }
__device__ __forceinline__ float silu_(float v){ return v*sig_(v); }
__device__ __forceinline__ float dsilu_(float v){ float s=sig_(v); return s*(1.0f + v*(1.0f-s)); }
__device__ __forceinline__ float clip1_(float v){ return fminf(fmaxf(v,-1.0f),1.0f); }
// row index m=(b,c) -> flat [b*S + nc*64 + c]*D + d
__device__ __forceinline__ size_t cidx(int m, int d, int nc){
  return ((size_t)((m>>6)*Ss) + nc*CSc + (m&63))*Dd + d;
}

// ---- coherent-point (L3) accessors: volatile => sc0 sc1, bypass L1/L2 ----------
__device__ __forceinline__ u8v  vld8 (const ushort_t* a){ return *(const volatile u8v*)a; }
__device__ __forceinline__ f4x  vld4f(const float* a)   { return *(const volatile f4x*)a; }
__device__ __forceinline__ void vst1 (ushort_t* a, ushort_t v){ *(volatile ushort_t*)a = v; }
__device__ __forceinline__ float vldf(const float* a)   { return *(const volatile float*)a; }
__device__ __forceinline__ void vstf (float* a, float v){ *(volatile float*)a = v; }
__device__ __forceinline__ ushort_t vldu(const ushort_t* a){ return *(const volatile ushort_t*)a; }

// ================= MFMA bf16 GEMM body: 64x64 tile, 4 waves 2x2, BK=32 ==========
// Scan-internal intermediates are accessed VOLATILE (coherence point) so the
// persistent kernel needs no L2 writeback/invalidate at grid barriers.
template<int PHASE, int KD>
__device__ __forceinline__ void gemm_body(const Ptrs& p, int nc, int bx, int by,
                                          const float* Wp, ushort_t* Cp,
                                          ushort_t* As, ushort_t* Bs) {
  constexpr int BK=32, STR=40;   // STR shorts = 80B, 16B-aligned rows
  const int tid = threadIdx.x;
  const int m0 = bx*64, n0 = by*64;
  const int wave = tid>>6, lane = tid&63;
  const int wm = wave&1, wn = wave>>1;
  const int quad = lane>>4, l16 = lane&15;

  f4v zz = {0.f,0.f,0.f,0.f};
  f4v acc[2][2];
  acc[0][0]=zz; acc[0][1]=zz; acc[1][0]=zz; acc[1][1]=zz;

  for (int k0=0; k0<KD; k0+=BK) {
    // ---------------- stage A (As[mm][kk], bf16) ----------------
    if constexpr (PHASE==PH_UPD1 || PHASE==PH_UPD2) {
      // A[m][k] = src[k][m] (transposed): read contiguous m, scatter to LDS
      int kk = tid>>3, mm0 = (tid&7)*8;
      u8v v;
      if constexpr (PHASE==PH_UPD1) v = vld8(&p.d1b[(size_t)(k0+kk)*Hh + m0+mm0]);
      else                          v = vld8(&p.d2b[(size_t)(k0+kk)*Dd + m0+mm0]);
      #pragma unroll
      for (int j=0;j<8;j++) As[(mm0+j)*STR + kk] = v[j];
    } else if constexpr (PHASE==PH_PROJ) {
      int mm = tid>>2, kk0 = (tid&3)*8;
      const float* s = &p.x[(size_t)(m0+mm)*Dd + (k0+kk0)];
      float4 f0 = *(const float4*)s, f1 = *(const float4*)(s+4);
      u8v o; o[0]=f2b(f0.x);o[1]=f2b(f0.y);o[2]=f2b(f0.z);o[3]=f2b(f0.w);
             o[4]=f2b(f1.x);o[5]=f2b(f1.y);o[6]=f2b(f1.z);o[7]=f2b(f1.w);
      *(u8v*)&As[mm*STR + kk0] = o;
    } else {
      int mm = tid>>2, kk0 = (tid&3)*8;
      int m = m0+mm, k = k0+kk0;
      u8v av;
      if constexpr (PHASE==PH_H1)        av = *(const u8v*)&p.kbuf[cidx(m,k,nc)];
      else if constexpr (PHASE==PH_H1Q)  av = *(const u8v*)&p.qbuf[cidx(m,k,nc)];
      else if constexpr (PHASE==PH_PRED) av = vld8(&p.a1[(size_t)m*Hh+k]);
      else if constexpr (PHASE==PH_R)    av = vld8(&p.d1b[(size_t)m*Hh+k]);
      else if constexpr (PHASE==PH_D1)   av = vld8(&p.d2b[(size_t)m*Dd+k]);
      else /*PH_OUTC*/                   av = vld8(&p.rbuf[(size_t)m*Dd+k]);
      *(u8v*)&As[mm*STR + kk0] = av;
    }
    // ---------------- stage B (Bs[nn][kk] = B[k][n] with n-major rows) ----------
    if constexpr (PHASE==PH_D1) {
      // B[n=h][k=d] = E2[d][h]: read 8 consecutive h for fixed d, scatter
      int kk = tid>>3, nn0 = (tid&7)*8;
      size_t off = (size_t)(k0+kk)*Hh + (n0+nn0);
      float4 a0 = *(const float4*)&p.W2[off],  a1_ = *(const float4*)&p.W2[off+4];
      f4x b0 = vld4f(&p.Wd2[off]); f4x b1_ = vld4f(&p.Wd2[off+4]);
      Bs[(nn0+0)*STR+kk]=f2b(a0.x+b0[0]); Bs[(nn0+1)*STR+kk]=f2b(a0.y+b0[1]);
      Bs[(nn0+2)*STR+kk]=f2b(a0.z+b0[2]); Bs[(nn0+3)*STR+kk]=f2b(a0.w+b0[3]);
      Bs[(nn0+4)*STR+kk]=f2b(a1_.x+b1_[0]); Bs[(nn0+5)*STR+kk]=f2b(a1_.y+b1_[1]);
      Bs[(nn0+6)*STR+kk]=f2b(a1_.z+b1_[2]); Bs[(nn0+7)*STR+kk]=f2b(a1_.w+b1_[3]);
    } else if constexpr (PHASE==PH_UPD1) {
      // B[n=d][k=token] = kch[token][d]  (pre-scan data: cached)
      int kk = tid>>3, nn0 = (tid&7)*8;
      u8v v = *(const u8v*)&p.kbuf[cidx(k0+kk, n0+nn0, nc)];
      #pragma unroll
      for (int j=0;j<8;j++) Bs[(nn0+j)*STR + kk] = v[j];
    } else if constexpr (PHASE==PH_UPD2) {
      // B[n=h][k=token] = a1[token][h]  (scan intermediate: volatile)
      int kk = tid>>3, nn0 = (tid&7)*8;
      u8v v = vld8(&p.a1[(size_t)(k0+kk)*Hh + (n0+nn0)]);
      #pragma unroll
      for (int j=0;j<8;j++) Bs[(nn0+j)*STR + kk] = v[j];
    } else {
      // row-major fp32 B[n][k]: const weight cached, Wd (scan state) volatile
      int nn = tid>>2, kk0 = (tid&3)*8;
      int n = n0+nn, k = k0+kk0;
      const float *s1, *s2 = nullptr;
      if constexpr (PHASE==PH_PROJ)      { s1 = &Wp[(size_t)n*Dd+k]; }
      else if constexpr (PHASE==PH_OUTC) { s1 = &p.Wout[(size_t)n*Dd+k]; }
      else if constexpr (PHASE==PH_H1 || PHASE==PH_H1Q)
           { s1 = &p.W1[(size_t)n*Dd+k]; s2 = &p.Wd1[(size_t)n*Dd+k]; }
      else /*PRED,R*/
           { s1 = &p.W2[(size_t)n*Hh+k]; s2 = &p.Wd2[(size_t)n*Hh+k]; }
      float4 f0 = *(const float4*)s1, f1 = *(const float4*)(s1+4);
      if (s2) {
        f4x g0 = vld4f(s2), g1 = vld4f(s2+4);
        f0.x+=g0[0]; f0.y+=g0[1]; f0.z+=g0[2]; f0.w+=g0[3];
        f1.x+=g1[0]; f1.y+=g1[1]; f1.z+=g1[2]; f1.w+=g1[3];
      }
      u8v o; o[0]=f2b(f0.x);o[1]=f2b(f0.y);o[2]=f2b(f0.z);o[3]=f2b(f0.w);
             o[4]=f2b(f1.x);o[5]=f2b(f1.y);o[6]=f2b(f1.z);o[7]=f2b(f1.w);
      *(u8v*)&Bs[nn*STR + kk0] = o;
    }
    __syncthreads();
    // ---------------- MFMA ----------------
    s8v a0 = *(const s8v*)&As[(wm*32 +  0 + l16)*STR + quad*8];
    s8v a1f= *(const s8v*)&As[(wm*32 + 16 + l16)*STR + quad*8];
    s8v b0 = *(const s8v*)&Bs[(wn*32 +  0 + l16)*STR + quad*8];
    s8v b1f= *(const s8v*)&Bs[(wn*32 + 16 + l16)*STR + quad*8];
    acc[0][0] = __builtin_amdgcn_mfma_f32_16x16x32_bf16(a0,  b0,  acc[0][0], 0,0,0);
    acc[0][1] = __builtin_amdgcn_mfma_f32_16x16x32_bf16(a0,  b1f, acc[0][1], 0,0,0);
    acc[1][0] = __builtin_amdgcn_mfma_f32_16x16x32_bf16(a1f, b0,  acc[1][0], 0,0,0);
    acc[1][1] = __builtin_amdgcn_mfma_f32_16x16x32_bf16(a1f, b1f, acc[1][1], 0,0,0);
    __syncthreads();
  }

  // ---------------- epilogue: D row = quad*4+r, col = l16 ----------------
  float al=0.f, lr=0.f, et=0.f;
  if constexpr (PHASE==PH_UPD1 || PHASE==PH_UPD2) {
    al = p.gates[nc]; lr = p.gates[NCn+nc]; et = p.gates[2*NCn+nc];
  }
  #pragma unroll
  for (int mf=0; mf<2; mf++) {
    #pragma unroll
    for (int nf=0; nf<2; nf++) {
      #pragma unroll
      for (int r=0; r<4; r++) {
        int m = m0 + wm*32 + mf*16 + quad*4 + r;
        int n = n0 + wn*32 + nf*16 + l16;
        float v = acc[mf][nf][r];
        if constexpr (PHASE==PH_PROJ)      Cp[(size_t)m*Dd+n] = f2b(v);
        else if constexpr (PHASE==PH_OUTC) p.out[cidx(m,n,nc)] = v;
        else if constexpr (PHASE==PH_H1) {
          vst1(&p.h1[(size_t)m*Hh+n], f2b(v));
          vst1(&p.a1[(size_t)m*Hh+n], f2b(silu_(v)));
        }
        else if constexpr (PHASE==PH_H1Q)  vst1(&p.d1b[(size_t)m*Hh+n], f2b(silu_(v)));
        else if constexpr (PHASE==PH_PRED) {
          float e = clip1_(v - b2f(p.vbuf[cidx(m,n,nc)]));
          vst1(&p.d2b[(size_t)m*Dd+n], f2b(0.03125f*e));   // scale = 2/CS
        }
        else if constexpr (PHASE==PH_R)    vst1(&p.rbuf[(size_t)m*Dd+n], f2b(v));
        else if constexpr (PHASE==PH_D1)
          vst1(&p.d1b[(size_t)m*Hh+n], f2b(v * dsilu_(b2f(vldu(&p.h1[(size_t)m*Hh+n])))));
        else if constexpr (PHASE==PH_UPD1) {
          float g = clip1_(v);
          size_t idx = (size_t)m*Dd+n;
          float m1 = et*vldf(&p.M1[idx]) - lr*g;
          vstf(&p.M1[idx], m1);
          vstf(&p.Wd1[idx], (1.0f-al)*vldf(&p.Wd1[idx]) + m1);
        }
        else if constexpr (PHASE==PH_UPD2) {
          float g = clip1_(v);
          size_t idx = (size_t)m*Hh+n;
          float m2 = et*vldf(&p.M2[idx]) - lr*g;
          vstf(&p.M2[idx], m2);
          vstf(&p.Wd2[idx], (1.0f-al)*vldf(&p.Wd2[idx]) + m2);
        }
      }
    }
  }
}

// ---------------- projections (massively parallel, stays a normal launch) -------
__global__ __launch_bounds__(256) void gk_proj(Ptrs p){
  __shared__ ushort_t As[64*40];
  __shared__ ushort_t Bs[64*40];
  const float* Wp = blockIdx.z==0 ? p.Wk : (blockIdx.z==1 ? p.Wv : p.Wq);
  ushort_t*    Cp = blockIdx.z==0 ? p.kbuf : (blockIdx.z==1 ? p.vbuf : p.qbuf);
  gemm_body<PH_PROJ,Dd>(p, 0, blockIdx.x, blockIdx.y, Wp, Cp, As, Bs);
}

// ---------------- fence-free grid barrier (monotonic counter, RELAXED only) -----
// Data visibility comes from volatile (sc0 sc1) accesses, NOT from cache flushes:
// producers' stores are drained (vmcnt) by __syncthreads before arrive; consumers'
// volatile loads bypass stale L1/L2. No buffer_wbl2/buffer_inv is ever emitted.
__device__ __forceinline__ void gridbar(unsigned* bar, unsigned target){
  __syncthreads();
  if (threadIdx.x==0){
    __hip_atomic_fetch_add(&bar[0], 1u, __ATOMIC_RELAXED, __HIP_MEMORY_SCOPE_AGENT);
    while (__hip_atomic_load(&bar[0], __ATOMIC_RELAXED, __HIP_MEMORY_SCOPE_AGENT) < target)
      __builtin_amdgcn_s_sleep(8);
  }
  __syncthreads();
  asm volatile("" ::: "memory");
}

// ---------------- persistent fused scan: 4 epochs/chunk, pipelined across chunks
// Epoch A: UPD1(nc)[128] + UPD2(nc)[128]
// Epoch B: H1Q(nc)[128] + H1(nc+1)[128]
// Epoch C: R(nc)[64]    + PRED(nc+1)[64]
// Epoch D: OUTC(nc)[64] + D1(nc+1)[128]
__global__ __launch_bounds__(256) void scan_k(Ptrs p, unsigned* bar){
  __shared__ ushort_t As[64*40];
  __shared__ ushort_t Bs[64*40];
  const int bid = blockIdx.x;
  unsigned ep = 0;

  // prologue: chunk 0 head of the dependency chain
  if (bid < 128) gemm_body<PH_H1,  Dd>(p, 0, bid>>4, bid&15, nullptr,nullptr, As,Bs);
  ep++; gridbar(bar, GRIDB*ep);
  if (bid < 64)  gemm_body<PH_PRED,Hh>(p, 0, bid>>3, bid&7,  nullptr,nullptr, As,Bs);
  ep++; gridbar(bar, GRIDB*ep);
  if (bid < 128) gemm_body<PH_D1,  Dd>(p, 0, bid>>4, bid&15, nullptr,nullptr, As,Bs);
  ep++; gridbar(bar, GRIDB*ep);

  for (int nc = 0; nc < NCn; ++nc) {
    const bool more = (nc+1 < NCn);
    // ---- Epoch A: weight updates (disjoint outputs Wd1/M1 vs Wd2/M2) ----
    if (bid < 128) gemm_body<PH_UPD1,MROW>(p, nc, bid>>3, bid&7, nullptr,nullptr, As,Bs);
    else           gemm_body<PH_UPD2,MROW>(p, nc, (bid-128)>>4, (bid-128)&15, nullptr,nullptr, As,Bs);
    ep++; gridbar(bar, GRIDB*ep);
    // ---- Epoch B: both consumers of Wd1_new ----
    if (bid < 128)      gemm_body<PH_H1Q,Dd>(p, nc,   bid>>4, bid&15, nullptr,nullptr, As,Bs);
    else if (more)      gemm_body<PH_H1, Dd>(p, nc+1, (bid-128)>>4, (bid-128)&15, nullptr,nullptr, As,Bs);
    ep++; gridbar(bar, GRIDB*ep);
    // ---- Epoch C: both consumers of Wd2_new ----
    if (bid < 64)               gemm_body<PH_R,   Hh>(p, nc,   bid>>3, bid&7, nullptr,nullptr, As,Bs);
    else if (bid < 128 && more) gemm_body<PH_PRED,Hh>(p, nc+1, (bid-64)>>3, (bid-64)&7, nullptr,nullptr, As,Bs);
    ep++; gridbar(bar, GRIDB*ep);
    // ---- Epoch D: output proj of nc + backward of nc+1 ----
    if (bid < 64)               gemm_body<PH_OUTC,Dd>(p, nc,   bid>>3, bid&7, nullptr,nullptr, As,Bs);
    else if (bid < 192 && more) gemm_body<PH_D1, Dd>(p, nc+1, (bid-64)>>4, (bid-64)&15, nullptr,nullptr, As,Bs);
    ep++; gridbar(bar, GRIDB*ep);
  }
}

// ---------------- zero helper ----------------------------------------------------
__global__ __launch_bounds__(256)
void zero_k(float* __restrict__ ptr, int n){
  int i = blockIdx.x*256 + threadIdx.x;
  int stride = gridDim.x*256;
  for (; i < n; i += stride) ptr[i] = 0.0f;
}

// ---------------- halo save (last 3 rows of each chunk, pre-conv) ----------------
__global__ void halo_k(const ushort_t* __restrict__ kbuf, const ushort_t* __restrict__ vbuf,
                       const ushort_t* __restrict__ qbuf, ushort_t* __restrict__ halo){
  int bid = blockIdx.x;
  int t = bid / (NCn*Bb);
  int rem = bid % (NCn*Bb);
  int nc = rem / Bb, b = rem % Bb;
  const ushort_t* src = (t==0)?kbuf:((t==1)?vbuf:qbuf);
  ushort_t* dst = halo + (((size_t)t*NCn + nc)*Bb + b)*3*Dd;
  for (int e = threadIdx.x; e < 3*Dd; e += 256){
    int j = e / Dd, d = e % Dd;
    int s = nc*CSc + 61 + j;
    dst[e] = src[((size_t)b*Ss + s)*Dd + d];
  }
}

// ---------------- in-place causal depthwise conv (K=4) ---------------------------
__global__ void conv_k(ushort_t* __restrict__ kbuf, ushort_t* __restrict__ vbuf, ushort_t* __restrict__ qbuf,
                       const float* __restrict__ ckw, const float* __restrict__ ckb,
                       const float* __restrict__ cvw, const float* __restrict__ cvb,
                       const float* __restrict__ cqw, const float* __restrict__ cqb,
                       const ushort_t* __restrict__ halo){
  int bid = blockIdx.x;
  int t = bid / (NCn*Bb);
  int rem = bid % (NCn*Bb);
  int nc = rem / Bb, b = rem % Bb;
  ushort_t* buf = (t==0)?kbuf:((t==1)?vbuf:qbuf);
  const float* cw = (t==0)?ckw:((t==1)?cvw:cqw);
  const float* cb = (t==0)?ckb:((t==1)?cvb:cqb);
  const ushort_t* hl = halo + (((size_t)t*NCn + (nc>0?nc-1:0))*Bb + b)*3*Dd;
  for (int rep=0; rep<2; ++rep){
    int d = threadIdx.x + rep*256;
    float w0 = cw[d*4+0], w1 = cw[d*4+1], w2 = cw[d*4+2], w3 = cw[d*4+3];
    float bias = cb[d];
    float p1, p2, p3;
    if (nc == 0) { p1=p2=p3=0.0f; }
    else { p1 = b2f(hl[2*Dd+d]); p2 = b2f(hl[1*Dd+d]); p3 = b2f(hl[0*Dd+d]); }
    ushort_t* row = buf + ((size_t)b*Ss + nc*CSc)*Dd + d;
    for (int c=0;c<CSc;++c){
      float cur = b2f(row[(size_t)c*Dd]);
      float o = w3*cur + w2*p1 + w1*p2 + w0*p3 + bias;
      p3 = p2; p2 = p1; p1 = cur;
      row[(size_t)c*Dd] = f2b(o);
    }
  }
}

// ---------------- per-chunk scalar gates -----------------------------------------
__global__ __launch_bounds__(256)
void gates_k(const float* __restrict__ x,
             const float* __restrict__ wd, const float* __restrict__ bd,
             const float* __restrict__ wl, const float* __restrict__ bl,
             const float* __restrict__ we, const float* __restrict__ be,
             float* __restrict__ gates){
  int nc = blockIdx.x;
  int wave = threadIdx.x >> 6, lane = threadIdx.x & 63;
  __shared__ float red[4][3];
  float accA=0.f, accL=0.f, accE=0.f;
  float bdv = bd[0], blv = bl[0], bev = be[0];
  for (int pi = wave; pi < Bb*CSc; pi += 4) {
    int b = pi / CSc, c = pi % CSc;
    const float* xr = x + ((size_t)b*Ss + nc*CSc + c)*Dd + lane*8;
    float da=0.f, dl=0.f, de=0.f;
    #pragma unroll
    for (int u=0;u<8;++u){
      float xv = xr[u];
      int d = lane*8+u;
      da += xv*wd[d]; dl += xv*wl[d]; de += xv*we[d];
    }
    #pragma unroll
    for (int off=32; off; off>>=1){
      da += __shfl_down(da, off);
      dl += __shfl_down(dl, off);
      de += __shfl_down(de, off);
    }
    if (lane==0){
      accA += sig_(da + bdv);
      accL += sig_(dl + blv);
      accE += sig_(de + bev);
    }
  }
  if (lane==0){ red[wave][0]=accA; red[wave][1]=accL; red[wave][2]=accE; }
  __syncthreads();
  if (threadIdx.x==0){
    float a=0.f,l=0.f,e=0.f;
    for (int w=0;w<4;w++){ a+=red[w][0]; l+=red[w][1]; e+=red[w][2]; }
    gates[nc]        = a*(1.0f/512.0f);
    gates[NCn+nc]    = l*(1.0f/512.0f);
    gates[2*NCn+nc]  = e*(1.0f/512.0f);
  }
}

extern "C" void kernel_launch(void* const* d_in, const int* in_sizes, int n_in,
                              void* d_out, int out_size, void* d_ws, size_t ws_size,
                              hipStream_t stream) {
  (void)in_sizes; (void)n_in; (void)out_size;
  const float* x       = (const float*)d_in[0];
  const float* Wk      = (const float*)d_in[1];
  const float* Wv      = (const float*)d_in[2];
  const float* Wq      = (const float*)d_in[3];
  const float* Wout    = (const float*)d_in[4];
  const float* ckw     = (const float*)d_in[5];
  const float* ckb     = (const float*)d_in[6];
  const float* cvw     = (const float*)d_in[7];
  const float* cvb     = (const float*)d_in[8];
  const float* cqw     = (const float*)d_in[9];
  const float* cqb     = (const float*)d_in[10];
  const float* w_decay = (const float*)d_in[11];
  const float* b_decay = (const float*)d_in[12];
  const float* w_lr    = (const float*)d_in[13];
  const float* b_lr    = (const float*)d_in[14];
  const float* w_eta   = (const float*)d_in[15];
  const float* b_eta   = (const float*)d_in[16];
  const float* W1      = (const float*)d_in[17];
  const float* W2      = (const float*)d_in[18];

  // ---- workspace carve: fp32 state first, then bf16 buffers ----
  char* base = (char*)d_ws;
  size_t off = 0;
  auto alloc_f = [&](size_t n)->float*   { float* r=(float*)(base+off);   off += n*4; return r; };
  auto alloc_b = [&](size_t n)->ushort_t*{ ushort_t* r=(ushort_t*)(base+off); off += n*2; off=(off+15)&~15ull; return r; };

  float* Wd1  = alloc_f((size_t)Hh*Dd);
  float* M1   = alloc_f((size_t)Hh*Dd);
  float* Wd2  = alloc_f((size_t)Dd*Hh);
  float* M2   = alloc_f((size_t)Dd*Hh);
  float* gates= alloc_f(3*NCn + 4);
  float* barf = alloc_f(4);               // grid-barrier state (zeroed per launch)

  const size_t BSD = (size_t)Bb*Ss*Dd;
  ushort_t* kbuf = alloc_b(BSD);
  ushort_t* vbuf = alloc_b(BSD);
  ushort_t* qbuf = alloc_b(BSD);
  ushort_t* halo = alloc_b((size_t)3*NCn*Bb*3*Dd);
  ushort_t* h1   = alloc_b((size_t)MROW*Hh);
  ushort_t* a1   = alloc_b((size_t)MROW*Hh);
  ushort_t* d1b  = alloc_b((size_t)MROW*Hh);
  ushort_t* d2b  = alloc_b((size_t)MROW*Dd);
  ushort_t* rbuf = alloc_b((size_t)MROW*Dd);

  if (ws_size < off) return;  // clean fail instead of fault

  // zero scan state (Wd1,M1,Wd2,M2 contiguous) + barrier words
  zero_k<<<512, 256, 0, stream>>>(Wd1, 4*Hh*Dd);
  zero_k<<<1, 64, 0, stream>>>(barf, 4);

  Ptrs p;
  p.x=x; p.Wk=Wk; p.Wv=Wv; p.Wq=Wq; p.Wout=Wout; p.W1=W1; p.W2=W2;
  p.kbuf=kbuf; p.vbuf=vbuf; p.qbuf=qbuf; p.rbuf=rbuf;
  p.h1=h1; p.a1=a1; p.d1b=d1b; p.d2b=d2b;
  p.Wd1=Wd1; p.M1=M1; p.Wd2=Wd2; p.M2=M2;
  p.gates=gates; p.out=(float*)d_out;

  // projections: k/v/q = bf16(x) @ bf16(W^T)
  gk_proj<<<dim3(Bb*Ss/64, Dd/64, 3), 256, 0, stream>>>(p);
  halo_k<<<3*NCn*Bb, 256, 0, stream>>>(kbuf, vbuf, qbuf, halo);
  conv_k<<<3*NCn*Bb, 256, 0, stream>>>(kbuf, vbuf, qbuf, ckw, ckb, cvw, cvb, cqw, cqb, halo);
  gates_k<<<NCn, 256, 0, stream>>>(x, w_decay, b_decay, w_lr, b_lr, w_eta, b_eta, gates);

  // fused persistent chunk scan: 1 launch, 259 fence-free grid barriers
  scan_k<<<GRIDB, 256, 0, stream>>>(p, (unsigned*)barf);
}

// Round 3
// 8097.086 us; speedup vs baseline: 3.7526x; 1.2547x over previous
//
#include <hip/hip_runtime.h>

#define Bb 8
#define Ss 4096
#define Dd 512
#define Hh 1024
#define CSc 64
#define NCn 64
#define MROW 512  // Bb*CSc
#define GRIDB 256 // persistent scan grid (1 block/CU)

typedef unsigned short ushort_t;
typedef short s8v __attribute__((ext_vector_type(8)));          // 8 bf16 for MFMA A/B
typedef unsigned short u8v __attribute__((ext_vector_type(8))); // raw 8x bf16 storage
typedef float f4v __attribute__((ext_vector_type(4)));          // MFMA C/D
typedef float f4x __attribute__((ext_vector_type(4)));          // 16B float vector

enum { PH_PROJ=0, PH_H1, PH_PRED, PH_D1, PH_UPD1, PH_UPD2, PH_H1Q, PH_R, PH_OUTC };

struct Ptrs {
  const float *x, *Wk, *Wv, *Wq, *Wout, *W1, *W2;
  ushort_t *kbuf, *vbuf, *qbuf, *rbuf;
  ushort_t *h1, *a1, *d1b, *d2b;
  float *Wd1, *M1, *Wd2, *M2;
  float *gates;
  float *out;
};

__device__ __forceinline__ float b2f(ushort_t u){
  union { unsigned int i; float f; } c; c.i = ((unsigned int)u) << 16; return c.f;
}
__device__ __forceinline__ ushort_t f2b(float f){
  union { float f; unsigned int i; } c; c.f = f;
  unsigned int i = c.i;
  i += 0x7fffu + ((i >> 16) & 1u);   // RTNE
  return (ushort_t)(i >> 16);
}
__device__ __forceinline__ float sig_(float v){ return 1.0f/(1.0f+__expf(-v)); }
__device__ __forceinline__ float silu_(float v){ return v*sig_(v); }
__device__ __forceinline__ float dsilu_(float v){ float s=sig_(v); return s*(1.0f + v*(1.0f-s)); }
__device__ __forceinline__ float clip1_(float v){ return fminf(fmaxf(v,-1.0f),1.0f); }
// row index m=(b,c) -> flat [b*S + nc*64 + c]*D + d
__device__ __forceinline__ size_t cidx(int m, int d, int nc){
  return ((size_t)((m>>6)*Ss) + nc*CSc + (m&63))*Dd + d;
}

// ---- coherent-point accessors: volatile => bypass L1/L2, served at L3 ----------
__device__ __forceinline__ u8v  vld8 (const ushort_t* a){ return *(const volatile u8v*)a; }
__device__ __forceinline__ f4x  vld4f(const float* a)   { return *(const volatile f4x*)a; }
__device__ __forceinline__ void vst1 (ushort_t* a, ushort_t v){ *(volatile ushort_t*)a = v; }
__device__ __forceinline__ float vldf(const float* a)   { return *(const volatile float*)a; }
__device__ __forceinline__ void vstf (float* a, float v){ *(volatile float*)a = v; }
__device__ __forceinline__ ushort_t vldu(const ushort_t* a){ return *(const volatile ushort_t*)a; }

// ======================= staging: register prefetch state =======================
struct Stage {
  u8v a0, a1;                 // A bf16 paths
  f4x af0, af1, af2, af3;     // A fp32 (PROJ)
  f4x w0, w1, w2, w3;         // B fp32 weights
  f4x d0, d1, d2, d3;         // B Wd (volatile)
  u8v b0, b1;                 // B bf16 paths
};

template<int PHASE>
__device__ __forceinline__ void stage_load(const Ptrs& p, int nc, int k0,
                                           int m0, int n0, const float* Wp, Stage& sg){
  const int tid = threadIdx.x;
  // ---------- A ----------
  if constexpr (PHASE==PH_UPD1 || PHASE==PH_UPD2){
    int kk = tid>>2, mm0 = (tid&3)*16;
    if constexpr (PHASE==PH_UPD1){
      const ushort_t* s = &p.d1b[(size_t)(k0+kk)*Hh + m0+mm0];
      sg.a0 = vld8(s); sg.a1 = vld8(s+8);
    } else {
      const ushort_t* s = &p.d2b[(size_t)(k0+kk)*Dd + m0+mm0];
      sg.a0 = vld8(s); sg.a1 = vld8(s+8);
    }
  } else if constexpr (PHASE==PH_PROJ){
    int mm = tid>>2, kk0 = (tid&3)*16;
    const float* s = &p.x[(size_t)(m0+mm)*Dd + k0+kk0];
    sg.af0 = *(const f4x*)s;     sg.af1 = *(const f4x*)(s+4);
    sg.af2 = *(const f4x*)(s+8); sg.af3 = *(const f4x*)(s+12);
  } else {
    int mm = tid>>2, kk0 = (tid&3)*16;
    int m = m0+mm, k = k0+kk0;
    if constexpr (PHASE==PH_H1){
      const ushort_t* s = &p.kbuf[cidx(m,k,nc)];
      sg.a0 = *(const u8v*)s; sg.a1 = *(const u8v*)(s+8);
    } else if constexpr (PHASE==PH_H1Q){
      const ushort_t* s = &p.qbuf[cidx(m,k,nc)];
      sg.a0 = *(const u8v*)s; sg.a1 = *(const u8v*)(s+8);
    } else if constexpr (PHASE==PH_PRED){
      const ushort_t* s = &p.a1[(size_t)m*Hh+k];
      sg.a0 = vld8(s); sg.a1 = vld8(s+8);
    } else if constexpr (PHASE==PH_R){
      const ushort_t* s = &p.d1b[(size_t)m*Hh+k];
      sg.a0 = vld8(s); sg.a1 = vld8(s+8);
    } else if constexpr (PHASE==PH_D1){
      const ushort_t* s = &p.d2b[(size_t)m*Dd+k];
      sg.a0 = vld8(s); sg.a1 = vld8(s+8);
    } else { // PH_OUTC
      const ushort_t* s = &p.rbuf[(size_t)m*Dd+k];
      sg.a0 = vld8(s); sg.a1 = vld8(s+8);
    }
  }
  // ---------- B ----------
  if constexpr (PHASE==PH_D1){
    int kk = tid>>2, nn0 = (tid&3)*16;
    size_t off = (size_t)(k0+kk)*Hh + n0+nn0;
    sg.w0 = *(const f4x*)&p.W2[off];    sg.w1 = *(const f4x*)&p.W2[off+4];
    sg.w2 = *(const f4x*)&p.W2[off+8];  sg.w3 = *(const f4x*)&p.W2[off+12];
    sg.d0 = vld4f(&p.Wd2[off]);   sg.d1 = vld4f(&p.Wd2[off+4]);
    sg.d2 = vld4f(&p.Wd2[off+8]); sg.d3 = vld4f(&p.Wd2[off+12]);
  } else if constexpr (PHASE==PH_UPD1){
    int kk = tid>>2, nn0 = (tid&3)*16;
    const ushort_t* s = &p.kbuf[cidx(k0+kk, n0+nn0, nc)];
    sg.b0 = *(const u8v*)s; sg.b1 = *(const u8v*)(s+8);
  } else if constexpr (PHASE==PH_UPD2){
    int kk = tid>>2, nn0 = (tid&3)*16;
    const ushort_t* s = &p.a1[(size_t)(k0+kk)*Hh + n0+nn0];
    sg.b0 = vld8(s); sg.b1 = vld8(s+8);
  } else {
    int nn = tid>>2, kk0 = (tid&3)*16;
    int n = n0+nn, k = k0+kk0;
    const float *s1 = nullptr; const float* s2 = nullptr;
    if constexpr (PHASE==PH_PROJ)      { s1 = &Wp[(size_t)n*Dd+k]; }
    else if constexpr (PHASE==PH_OUTC) { s1 = &p.Wout[(size_t)n*Dd+k]; }
    else if constexpr (PHASE==PH_H1 || PHASE==PH_H1Q)
         { s1 = &p.W1[(size_t)n*Dd+k]; s2 = &p.Wd1[(size_t)n*Dd+k]; }
    else /*PRED,R*/
         { s1 = &p.W2[(size_t)n*Hh+k]; s2 = &p.Wd2[(size_t)n*Hh+k]; }
    sg.w0 = *(const f4x*)s1;     sg.w1 = *(const f4x*)(s1+4);
    sg.w2 = *(const f4x*)(s1+8); sg.w3 = *(const f4x*)(s1+12);
    if (s2){
      sg.d0 = vld4f(s2);   sg.d1 = vld4f(s2+4);
      sg.d2 = vld4f(s2+8); sg.d3 = vld4f(s2+12);
    }
  }
}

template<int PHASE>
__device__ __forceinline__ void stage_write(const Stage& sg, ushort_t* As, ushort_t* Bs){
  const int tid = threadIdx.x;
  constexpr int STR = 72;
  // ---------- A ----------
  if constexpr (PHASE==PH_UPD1 || PHASE==PH_UPD2){
    int kk = tid>>2, mm0 = (tid&3)*16;
    #pragma unroll
    for (int j=0;j<8;j++){
      As[(mm0+j)*STR+kk]   = sg.a0[j];
      As[(mm0+8+j)*STR+kk] = sg.a1[j];
    }
  } else if constexpr (PHASE==PH_PROJ){
    int mm = tid>>2, kk0 = (tid&3)*16;
    u8v o0, o1;
    o0[0]=f2b(sg.af0[0]); o0[1]=f2b(sg.af0[1]); o0[2]=f2b(sg.af0[2]); o0[3]=f2b(sg.af0[3]);
    o0[4]=f2b(sg.af1[0]); o0[5]=f2b(sg.af1[1]); o0[6]=f2b(sg.af1[2]); o0[7]=f2b(sg.af1[3]);
    o1[0]=f2b(sg.af2[0]); o1[1]=f2b(sg.af2[1]); o1[2]=f2b(sg.af2[2]); o1[3]=f2b(sg.af2[3]);
    o1[4]=f2b(sg.af3[0]); o1[5]=f2b(sg.af3[1]); o1[6]=f2b(sg.af3[2]); o1[7]=f2b(sg.af3[3]);
    *(u8v*)&As[mm*STR+kk0]   = o0;
    *(u8v*)&As[mm*STR+kk0+8] = o1;
  } else {
    int mm = tid>>2, kk0 = (tid&3)*16;
    *(u8v*)&As[mm*STR+kk0]   = sg.a0;
    *(u8v*)&As[mm*STR+kk0+8] = sg.a1;
  }
  // ---------- B ----------
  if constexpr (PHASE==PH_D1){
    int kk = tid>>2, nn0 = (tid&3)*16;
    Bs[(nn0+ 0)*STR+kk]=f2b(sg.w0[0]+sg.d0[0]); Bs[(nn0+ 1)*STR+kk]=f2b(sg.w0[1]+sg.d0[1]);
    Bs[(nn0+ 2)*STR+kk]=f2b(sg.w0[2]+sg.d0[2]); Bs[(nn0+ 3)*STR+kk]=f2b(sg.w0[3]+sg.d0[3]);
    Bs[(nn0+ 4)*STR+kk]=f2b(sg.w1[0]+sg.d1[0]); Bs[(nn0+ 5)*STR+kk]=f2b(sg.w1[1]+sg.d1[1]);
    Bs[(nn0+ 6)*STR+kk]=f2b(sg.w1[2]+sg.d1[2]); Bs[(nn0+ 7)*STR+kk]=f2b(sg.w1[3]+sg.d1[3]);
    Bs[(nn0+ 8)*STR+kk]=f2b(sg.w2[0]+sg.d2[0]); Bs[(nn0+ 9)*STR+kk]=f2b(sg.w2[1]+sg.d2[1]);
    Bs[(nn0+10)*STR+kk]=f2b(sg.w2[2]+sg.d2[2]); Bs[(nn0+11)*STR+kk]=f2b(sg.w2[3]+sg.d2[3]);
    Bs[(nn0+12)*STR+kk]=f2b(sg.w3[0]+sg.d3[0]); Bs[(nn0+13)*STR+kk]=f2b(sg.w3[1]+sg.d3[1]);
    Bs[(nn0+14)*STR+kk]=f2b(sg.w3[2]+sg.d3[2]); Bs[(nn0+15)*STR+kk]=f2b(sg.w3[3]+sg.d3[3]);
  } else if constexpr (PHASE==PH_UPD1 || PHASE==PH_UPD2){
    int kk = tid>>2, nn0 = (tid&3)*16;
    #pragma unroll
    for (int j=0;j<8;j++){
      Bs[(nn0+j)*STR+kk]   = sg.b0[j];
      Bs[(nn0+8+j)*STR+kk] = sg.b1[j];
    }
  } else {
    constexpr bool HASWD = (PHASE==PH_H1 || PHASE==PH_H1Q || PHASE==PH_PRED || PHASE==PH_R);
    int nn = tid>>2, kk0 = (tid&3)*16;
    u8v o0, o1;
    if constexpr (HASWD){
      o0[0]=f2b(sg.w0[0]+sg.d0[0]); o0[1]=f2b(sg.w0[1]+sg.d0[1]);
      o0[2]=f2b(sg.w0[2]+sg.d0[2]); o0[3]=f2b(sg.w0[3]+sg.d0[3]);
      o0[4]=f2b(sg.w1[0]+sg.d1[0]); o0[5]=f2b(sg.w1[1]+sg.d1[1]);
      o0[6]=f2b(sg.w1[2]+sg.d1[2]); o0[7]=f2b(sg.w1[3]+sg.d1[3]);
      o1[0]=f2b(sg.w2[0]+sg.d2[0]); o1[1]=f2b(sg.w2[1]+sg.d2[1]);
      o1[2]=f2b(sg.w2[2]+sg.d2[2]); o1[3]=f2b(sg.w2[3]+sg.d2[3]);
      o1[4]=f2b(sg.w3[0]+sg.d3[0]); o1[5]=f2b(sg.w3[1]+sg.d3[1]);
      o1[6]=f2b(sg.w3[2]+sg.d3[2]); o1[7]=f2b(sg.w3[3]+sg.d3[3]);
    } else {
      o0[0]=f2b(sg.w0[0]); o0[1]=f2b(sg.w0[1]); o0[2]=f2b(sg.w0[2]); o0[3]=f2b(sg.w0[3]);
      o0[4]=f2b(sg.w1[0]); o0[5]=f2b(sg.w1[1]); o0[6]=f2b(sg.w1[2]); o0[7]=f2b(sg.w1[3]);
      o1[0]=f2b(sg.w2[0]); o1[1]=f2b(sg.w2[1]); o1[2]=f2b(sg.w2[2]); o1[3]=f2b(sg.w2[3]);
      o1[4]=f2b(sg.w3[0]); o1[5]=f2b(sg.w3[1]); o1[6]=f2b(sg.w3[2]); o1[7]=f2b(sg.w3[3]);
    }
    *(u8v*)&Bs[nn*STR+kk0]   = o0;
    *(u8v*)&Bs[nn*STR+kk0+8] = o1;
  }
}

// ============ MFMA bf16 GEMM body: 64x64 tile, 4 waves 2x2, BK=64 dbuf ==========
// Double-buffered LDS + register prefetch: next tile's global loads issue before
// the current tile's MFMA, hiding L3 latency; ONE __syncthreads per K-step.
template<int PHASE, int KD>
__device__ __forceinline__ void gemm_body(const Ptrs& p, int nc, int bx, int by,
                                          const float* Wp, ushort_t* Cp,
                                          ushort_t* As, ushort_t* Bs) {
  constexpr int STR=72, BUF=64*STR;
  const int tid = threadIdx.x;
  const int m0 = bx*64, n0 = by*64;
  const int wave = tid>>6, lane = tid&63;
  const int wm = wave&1, wn = wave>>1;
  const int quad = lane>>4, l16 = lane&15;

  f4v zz = {0.f,0.f,0.f,0.f};
  f4v acc[2][2];
  acc[0][0]=zz; acc[0][1]=zz; acc[1][0]=zz; acc[1][1]=zz;

  Stage sg;
  stage_load<PHASE>(p, nc, 0, m0, n0, Wp, sg);
  stage_write<PHASE>(sg, As, Bs);
  __syncthreads();

  constexpr int NT = KD/64;
  #pragma unroll 2
  for (int t=0; t<NT; ++t){
    ushort_t* Ac = As + (t&1)*BUF;
    ushort_t* Bc = Bs + (t&1)*BUF;
    if (t+1<NT) stage_load<PHASE>(p, nc, (t+1)*64, m0, n0, Wp, sg);
    #pragma unroll
    for (int ks=0; ks<2; ++ks){
      s8v a0 = *(const s8v*)&Ac[(wm*32 +  0 + l16)*STR + ks*32 + quad*8];
      s8v a1f= *(const s8v*)&Ac[(wm*32 + 16 + l16)*STR + ks*32 + quad*8];
      s8v b0 = *(const s8v*)&Bc[(wn*32 +  0 + l16)*STR + ks*32 + quad*8];
      s8v b1f= *(const s8v*)&Bc[(wn*32 + 16 + l16)*STR + ks*32 + quad*8];
      acc[0][0] = __builtin_amdgcn_mfma_f32_16x16x32_bf16(a0,  b0,  acc[0][0], 0,0,0);
      acc[0][1] = __builtin_amdgcn_mfma_f32_16x16x32_bf16(a0,  b1f, acc[0][1], 0,0,0);
      acc[1][0] = __builtin_amdgcn_mfma_f32_16x16x32_bf16(a1f, b0,  acc[1][0], 0,0,0);
      acc[1][1] = __builtin_amdgcn_mfma_f32_16x16x32_bf16(a1f, b1f, acc[1][1], 0,0,0);
    }
    if (t+1<NT){
      stage_write<PHASE>(sg, As + ((t+1)&1)*BUF, Bs + ((t+1)&1)*BUF);
      __syncthreads();
    }
  }

  // ---------------- epilogue: D row = quad*4+r, col = l16 ----------------
  float al=0.f, lr=0.f, et=0.f;
  if constexpr (PHASE==PH_UPD1 || PHASE==PH_UPD2) {
    al = p.gates[nc]; lr = p.gates[NCn+nc]; et = p.gates[2*NCn+nc];
  }
  #pragma unroll
  for (int mf=0; mf<2; mf++) {
    #pragma unroll
    for (int nf=0; nf<2; nf++) {
      #pragma unroll
      for (int r=0; r<4; r++) {
        int m = m0 + wm*32 + mf*16 + quad*4 + r;
        int n = n0 + wn*32 + nf*16 + l16;
        float v = acc[mf][nf][r];
        if constexpr (PHASE==PH_PROJ)      Cp[(size_t)m*Dd+n] = f2b(v);
        else if constexpr (PHASE==PH_OUTC) p.out[cidx(m,n,nc)] = v;
        else if constexpr (PHASE==PH_H1) {
          vst1(&p.h1[(size_t)m*Hh+n], f2b(v));
          vst1(&p.a1[(size_t)m*Hh+n], f2b(silu_(v)));
        }
        else if constexpr (PHASE==PH_H1Q)  vst1(&p.d1b[(size_t)m*Hh+n], f2b(silu_(v)));
        else if constexpr (PHASE==PH_PRED) {
          float e = clip1_(v - b2f(p.vbuf[cidx(m,n,nc)]));
          vst1(&p.d2b[(size_t)m*Dd+n], f2b(0.03125f*e));   // scale = 2/CS
        }
        else if constexpr (PHASE==PH_R)    vst1(&p.rbuf[(size_t)m*Dd+n], f2b(v));
        else if constexpr (PHASE==PH_D1)
          vst1(&p.d1b[(size_t)m*Hh+n], f2b(v * dsilu_(b2f(vldu(&p.h1[(size_t)m*Hh+n])))));
        else if constexpr (PHASE==PH_UPD1) {
          float g = clip1_(v);
          size_t idx = (size_t)m*Dd+n;
          float m1 = et*vldf(&p.M1[idx]) - lr*g;
          vstf(&p.M1[idx], m1);
          vstf(&p.Wd1[idx], (1.0f-al)*vldf(&p.Wd1[idx]) + m1);
        }
        else if constexpr (PHASE==PH_UPD2) {
          float g = clip1_(v);
          size_t idx = (size_t)m*Hh+n;
          float m2 = et*vldf(&p.M2[idx]) - lr*g;
          vstf(&p.M2[idx], m2);
          vstf(&p.Wd2[idx], (1.0f-al)*vldf(&p.Wd2[idx]) + m2);
        }
      }
    }
  }
}

// ---------------- projections (massively parallel, stays a normal launch) -------
__global__ __launch_bounds__(256) void gk_proj(Ptrs p){
  __shared__ ushort_t As[2*64*72];
  __shared__ ushort_t Bs[2*64*72];
  const float* Wp = blockIdx.z==0 ? p.Wk : (blockIdx.z==1 ? p.Wv : p.Wq);
  ushort_t*    Cp = blockIdx.z==0 ? p.kbuf : (blockIdx.z==1 ? p.vbuf : p.qbuf);
  gemm_body<PH_PROJ,Dd>(p, 0, blockIdx.x, blockIdx.y, Wp, Cp, As, Bs);
}

// ---------------- atomic-free distributed grid barrier ---------------------------
// Each block volatile-stores its epoch into its OWN padded slot (no contention).
// Block 0's 256 threads each watch one slot; thread 0 then publishes the monotonic
// release word that all other blocks poll. Same volatile visibility mechanism as
// the data stores (validated by round 2 passing).
__device__ __forceinline__ void gridbar(volatile unsigned* arr, volatile unsigned* rel,
                                        unsigned ep){
  __syncthreads();                      // drains this block's data stores (vmcnt 0)
  if (blockIdx.x == 0){
    int t = threadIdx.x;
    if (t > 0 && t < GRIDB){
      while (arr[t*16] < ep) __builtin_amdgcn_s_sleep(2);
    }
    __syncthreads();                    // all watchers done
    if (t == 0) rel[0] = ep;
  } else {
    if (threadIdx.x == 0){
      arr[blockIdx.x*16] = ep;
      while (rel[0] < ep) __builtin_amdgcn_s_sleep(2);
    }
  }
  __syncthreads();
  asm volatile("" ::: "memory");
}

// ---------------- persistent fused scan: 4 epochs/chunk, pipelined across chunks
// Epoch A: UPD1(nc)[128] + UPD2(nc)[128]
// Epoch B: H1Q(nc)[128] + H1(nc+1)[128]
// Epoch C: R(nc)[64]    + PRED(nc+1)[64]
// Epoch D: OUTC(nc)[64] + D1(nc+1)[128]
__global__ __launch_bounds__(256) void scan_k(Ptrs p, unsigned* arr, unsigned* rel){
  __shared__ ushort_t As[2*64*72];
  __shared__ ushort_t Bs[2*64*72];
  const int bid = blockIdx.x;
  unsigned ep = 0;

  // prologue: chunk 0 head of the dependency chain
  if (bid < 128) gemm_body<PH_H1,  Dd>(p, 0, bid>>4, bid&15, nullptr,nullptr, As,Bs);
  gridbar(arr, rel, ++ep);
  if (bid < 64)  gemm_body<PH_PRED,Hh>(p, 0, bid>>3, bid&7,  nullptr,nullptr, As,Bs);
  gridbar(arr, rel, ++ep);
  if (bid < 128) gemm_body<PH_D1,  Dd>(p, 0, bid>>4, bid&15, nullptr,nullptr, As,Bs);
  gridbar(arr, rel, ++ep);

  for (int nc = 0; nc < NCn; ++nc) {
    const bool more = (nc+1 < NCn);
    // ---- Epoch A: weight updates (disjoint outputs Wd1/M1 vs Wd2/M2) ----
    if (bid < 128) gemm_body<PH_UPD1,MROW>(p, nc, bid>>3, bid&7, nullptr,nullptr, As,Bs);
    else           gemm_body<PH_UPD2,MROW>(p, nc, (bid-128)>>4, (bid-128)&15, nullptr,nullptr, As,Bs);
    gridbar(arr, rel, ++ep);
    // ---- Epoch B: both consumers of Wd1_new ----
    if (bid < 128)      gemm_body<PH_H1Q,Dd>(p, nc,   bid>>4, bid&15, nullptr,nullptr, As,Bs);
    else if (more)      gemm_body<PH_H1, Dd>(p, nc+1, (bid-128)>>4, (bid-128)&15, nullptr,nullptr, As,Bs);
    gridbar(arr, rel, ++ep);
    // ---- Epoch C: both consumers of Wd2_new ----
    if (bid < 64)               gemm_body<PH_R,   Hh>(p, nc,   bid>>3, bid&7, nullptr,nullptr, As,Bs);
    else if (bid < 128 && more) gemm_body<PH_PRED,Hh>(p, nc+1, (bid-64)>>3, (bid-64)&7, nullptr,nullptr, As,Bs);
    gridbar(arr, rel, ++ep);
    // ---- Epoch D: output proj of nc + backward of nc+1 ----
    if (bid < 64)               gemm_body<PH_OUTC,Dd>(p, nc,   bid>>3, bid&7, nullptr,nullptr, As,Bs);
    else if (bid < 192 && more) gemm_body<PH_D1, Dd>(p, nc+1, (bid-64)>>4, (bid-64)&15, nullptr,nullptr, As,Bs);
    gridbar(arr, rel, ++ep);
  }
}

// ---------------- zero helper ----------------------------------------------------
__global__ __launch_bounds__(256)
void zero_k(float* __restrict__ ptr, int n){
  int i = blockIdx.x*256 + threadIdx.x;
  int stride = gridDim.x*256;
  for (; i < n; i += stride) ptr[i] = 0.0f;
}

// ---------------- halo save (last 3 rows of each chunk, pre-conv) ----------------
__global__ void halo_k(const ushort_t* __restrict__ kbuf, const ushort_t* __restrict__ vbuf,
                       const ushort_t* __restrict__ qbuf, ushort_t* __restrict__ halo){
  int bid = blockIdx.x;
  int t = bid / (NCn*Bb);
  int rem = bid % (NCn*Bb);
  int nc = rem / Bb, b = rem % Bb;
  const ushort_t* src = (t==0)?kbuf:((t==1)?vbuf:qbuf);
  ushort_t* dst = halo + (((size_t)t*NCn + nc)*Bb + b)*3*Dd;
  for (int e = threadIdx.x; e < 3*Dd; e += 256){
    int j = e / Dd, d = e % Dd;
    int s = nc*CSc + 61 + j;
    dst[e] = src[((size_t)b*Ss + s)*Dd + d];
  }
}

// ---------------- in-place causal depthwise conv (K=4) ---------------------------
__global__ void conv_k(ushort_t* __restrict__ kbuf, ushort_t* __restrict__ vbuf, ushort_t* __restrict__ qbuf,
                       const float* __restrict__ ckw, const float* __restrict__ ckb,
                       const float* __restrict__ cvw, const float* __restrict__ cvb,
                       const float* __restrict__ cqw, const float* __restrict__ cqb,
                       const ushort_t* __restrict__ halo){
  int bid = blockIdx.x;
  int t = bid / (NCn*Bb);
  int rem = bid % (NCn*Bb);
  int nc = rem / Bb, b = rem % Bb;
  ushort_t* buf = (t==0)?kbuf:((t==1)?vbuf:qbuf);
  const float* cw = (t==0)?ckw:((t==1)?cvw:cqw);
  const float* cb = (t==0)?ckb:((t==1)?cvb:cqb);
  const ushort_t* hl = halo + (((size_t)t*NCn + (nc>0?nc-1:0))*Bb + b)*3*Dd;
  for (int rep=0; rep<2; ++rep){
    int d = threadIdx.x + rep*256;
    float w0 = cw[d*4+0], w1 = cw[d*4+1], w2 = cw[d*4+2], w3 = cw[d*4+3];
    float bias = cb[d];
    float p1, p2, p3;
    if (nc == 0) { p1=p2=p3=0.0f; }
    else { p1 = b2f(hl[2*Dd+d]); p2 = b2f(hl[1*Dd+d]); p3 = b2f(hl[0*Dd+d]); }
    ushort_t* row = buf + ((size_t)b*Ss + nc*CSc)*Dd + d;
    for (int c=0;c<CSc;++c){
      float cur = b2f(row[(size_t)c*Dd]);
      float o = w3*cur + w2*p1 + w1*p2 + w0*p3 + bias;
      p3 = p2; p2 = p1; p1 = cur;
      row[(size_t)c*Dd] = f2b(o);
    }
  }
}

// ---------------- per-chunk scalar gates -----------------------------------------
__global__ __launch_bounds__(256)
void gates_k(const float* __restrict__ x,
             const float* __restrict__ wd, const float* __restrict__ bd,
             const float* __restrict__ wl, const float* __restrict__ bl,
             const float* __restrict__ we, const float* __restrict__ be,
             float* __restrict__ gates){
  int nc = blockIdx.x;
  int wave = threadIdx.x >> 6, lane = threadIdx.x & 63;
  __shared__ float red[4][3];
  float accA=0.f, accL=0.f, accE=0.f;
  float bdv = bd[0], blv = bl[0], bev = be[0];
  for (int pi = wave; pi < Bb*CSc; pi += 4) {
    int b = pi / CSc, c = pi % CSc;
    const float* xr = x + ((size_t)b*Ss + nc*CSc + c)*Dd + lane*8;
    float da=0.f, dl=0.f, de=0.f;
    #pragma unroll
    for (int u=0;u<8;++u){
      float xv = xr[u];
      int d = lane*8+u;
      da += xv*wd[d]; dl += xv*wl[d]; de += xv*we[d];
    }
    #pragma unroll
    for (int off=32; off; off>>=1){
      da += __shfl_down(da, off);
      dl += __shfl_down(dl, off);
      de += __shfl_down(de, off);
    }
    if (lane==0){
      accA += sig_(da + bdv);
      accL += sig_(dl + blv);
      accE += sig_(de + bev);
    }
  }
  if (lane==0){ red[wave][0]=accA; red[wave][1]=accL; red[wave][2]=accE; }
  __syncthreads();
  if (threadIdx.x==0){
    float a=0.f,l=0.f,e=0.f;
    for (int w=0;w<4;w++){ a+=red[w][0]; l+=red[w][1]; e+=red[w][2]; }
    gates[nc]        = a*(1.0f/512.0f);
    gates[NCn+nc]    = l*(1.0f/512.0f);
    gates[2*NCn+nc]  = e*(1.0f/512.0f);
  }
}

extern "C" void kernel_launch(void* const* d_in, const int* in_sizes, int n_in,
                              void* d_out, int out_size, void* d_ws, size_t ws_size,
                              hipStream_t stream) {
  (void)in_sizes; (void)n_in; (void)out_size;
  const float* x       = (const float*)d_in[0];
  const float* Wk      = (const float*)d_in[1];
  const float* Wv      = (const float*)d_in[2];
  const float* Wq      = (const float*)d_in[3];
  const float* Wout    = (const float*)d_in[4];
  const float* ckw     = (const float*)d_in[5];
  const float* ckb     = (const float*)d_in[6];
  const float* cvw     = (const float*)d_in[7];
  const float* cvb     = (const float*)d_in[8];
  const float* cqw     = (const float*)d_in[9];
  const float* cqb     = (const float*)d_in[10];
  const float* w_decay = (const float*)d_in[11];
  const float* b_decay = (const float*)d_in[12];
  const float* w_lr    = (const float*)d_in[13];
  const float* b_lr    = (const float*)d_in[14];
  const float* w_eta   = (const float*)d_in[15];
  const float* b_eta   = (const float*)d_in[16];
  const float* W1      = (const float*)d_in[17];
  const float* W2      = (const float*)d_in[18];

  // ---- workspace carve: fp32 state first, then bf16 buffers ----
  char* base = (char*)d_ws;
  size_t off = 0;
  auto alloc_f = [&](size_t n)->float*   { float* r=(float*)(base+off);   off += n*4; return r; };
  auto alloc_b = [&](size_t n)->ushort_t*{ ushort_t* r=(ushort_t*)(base+off); off += n*2; off=(off+15)&~15ull; return r; };

  float* Wd1  = alloc_f((size_t)Hh*Dd);
  float* M1   = alloc_f((size_t)Hh*Dd);
  float* Wd2  = alloc_f((size_t)Dd*Hh);
  float* M2   = alloc_f((size_t)Dd*Hh);
  float* gates= alloc_f(3*NCn + 4);
  float* barf = alloc_f(GRIDB*16 + 16);   // arrive slots (64B-padded) + release word

  const size_t BSD = (size_t)Bb*Ss*Dd;
  ushort_t* kbuf = alloc_b(BSD);
  ushort_t* vbuf = alloc_b(BSD);
  ushort_t* qbuf = alloc_b(BSD);
  ushort_t* halo = alloc_b((size_t)3*NCn*Bb*3*Dd);
  ushort_t* h1   = alloc_b((size_t)MROW*Hh);
  ushort_t* a1   = alloc_b((size_t)MROW*Hh);
  ushort_t* d1b  = alloc_b((size_t)MROW*Hh);
  ushort_t* d2b  = alloc_b((size_t)MROW*Dd);
  ushort_t* rbuf = alloc_b((size_t)MROW*Dd);

  if (ws_size < off) return;  // clean fail instead of fault

  // zero scan state (Wd1,M1,Wd2,M2,gates,barrier contiguous fp32 block)
  zero_k<<<1024, 256, 0, stream>>>(Wd1, 4*Hh*Dd + (3*NCn+4) + (GRIDB*16+16));

  Ptrs p;
  p.x=x; p.Wk=Wk; p.Wv=Wv; p.Wq=Wq; p.Wout=Wout; p.W1=W1; p.W2=W2;
  p.kbuf=kbuf; p.vbuf=vbuf; p.qbuf=qbuf; p.rbuf=rbuf;
  p.h1=h1; p.a1=a1; p.d1b=d1b; p.d2b=d2b;
  p.Wd1=Wd1; p.M1=M1; p.Wd2=Wd2; p.M2=M2;
  p.gates=gates; p.out=(float*)d_out;

  unsigned* arr = (unsigned*)barf;
  unsigned* rel = (unsigned*)(barf + GRIDB*16);

  // projections: k/v/q = bf16(x) @ bf16(W^T)
  gk_proj<<<dim3(Bb*Ss/64, Dd/64, 3), 256, 0, stream>>>(p);
  halo_k<<<3*NCn*Bb, 256, 0, stream>>>(kbuf, vbuf, qbuf, halo);
  conv_k<<<3*NCn*Bb, 256, 0, stream>>>(kbuf, vbuf, qbuf, ckw, ckb, cvw, cvb, cqw, cqb, halo);
  gates_k<<<NCn, 256, 0, stream>>>(x, w_decay, b_decay, w_lr, b_lr, w_eta, b_eta, gates);

  // fused persistent chunk scan: 1 launch, 259 atomic-free grid barriers
  scan_k<<<GRIDB, 256, 0, stream>>>(p, arr, rel);
}

// Round 4
// 6965.400 us; speedup vs baseline: 4.3623x; 1.1625x over previous
//
#include <hip/hip_runtime.h>

#define Bb 8
#define Ss 4096
#define Dd 512
#define Hh 1024
#define CSc 64
#define NCn 64
#define MROW 512  // Bb*CSc
#define GRIDB 256 // persistent scan grid (1 block/CU)

typedef unsigned short ushort_t;
typedef short s8v __attribute__((ext_vector_type(8)));          // 8 bf16 for MFMA A/B
typedef unsigned short u8v __attribute__((ext_vector_type(8))); // raw 8x bf16 storage
typedef float f4v __attribute__((ext_vector_type(4)));          // MFMA C/D
typedef float f4x __attribute__((ext_vector_type(4)));          // 16B float vector

enum { PH_PROJ=0, PH_H1, PH_PRED, PH_D1, PH_UPD1, PH_UPD2, PH_H1Q, PH_R, PH_OUTC };

struct Ptrs {
  const float *x, *Wk, *Wv, *Wq, *Wout, *W1, *W2;
  ushort_t *kbuf, *vbuf, *qbuf, *rbuf;
  ushort_t *h1, *a1, *d1b, *d2b;
  ushort_t *e1, *e2;            // bf16 effective weights f2b(W+Wd), written at UPD
  float *Wd1, *M1, *Wd2, *M2;   // block-private cached state (fixed tile->bid map)
  float *gates;
  float *out;
};

__device__ __forceinline__ float b2f(ushort_t u){
  union { unsigned int i; float f; } c; c.i = ((unsigned int)u) << 16; return c.f;
}
__device__ __forceinline__ ushort_t f2b(float f){
  union { float f; unsigned int i; } c; c.f = f;
  unsigned int i = c.i;
  i += 0x7fffu + ((i >> 16) & 1u);   // RTNE
  return (ushort_t)(i >> 16);
}
__device__ __forceinline__ float sig_(float v){ return 1.0f/(1.0f+__expf(-v)); }
__device__ __forceinline__ float silu_(float v){ return v*sig_(v); }
__device__ __forceinline__ float dsilu_(float v){ float s=sig_(v); return s*(1.0f + v*(1.0f-s)); }
__device__ __forceinline__ float clip1_(float v){ return fminf(fmaxf(v,-1.0f),1.0f); }
// row index m=(b,c) -> flat [b*S + nc*64 + c]*D + d
__device__ __forceinline__ size_t cidx(int m, int d, int nc){
  return ((size_t)((m>>6)*Ss) + nc*CSc + (m&63))*Dd + d;
}

// ---- coherent-point accessors: volatile => bypass L1/L2 (cross-block data) -----
__device__ __forceinline__ void vst1 (ushort_t* a, ushort_t v){ *(volatile ushort_t*)a = v; }
__device__ __forceinline__ ushort_t vldu(const ushort_t* a){ return *(const volatile ushort_t*)a; }

template<bool VOL>
__device__ __forceinline__ u8v ld8(const ushort_t* a){
  if constexpr (VOL) return *(const volatile u8v*)a;
  else               return *(const u8v*)a;
}

// ---- LDS: 64 x 512 shorts per panel, XOR-swizzled (bank-conflict-free b128) ----
__device__ __forceinline__ int swz(int r, int c){ return r*512 + (c ^ ((r&7)<<3)); }

// ======================= whole-panel staging (K=512) ============================
// Row-major bf16 source: Dst[r][c] = base[r*stride + kp + c]
template<bool VOL>
__device__ __forceinline__ void stage_rows_bf16(const ushort_t* base, size_t stride,
                                                int kp, ushort_t* Dst){
  const int tid = threadIdx.x;
  const int r = tid>>2, c0 = (tid&3)*128;
  const ushort_t* s = base + (size_t)r*stride + kp + c0;
  #pragma unroll
  for (int j=0;j<16;j++){
    u8v v = ld8<VOL>(s + j*8);
    *(u8v*)&Dst[swz(r, c0 + j*8)] = v;
  }
}
// Row-major fp32 source (cached weights): convert to bf16
__device__ __forceinline__ void stage_rows_f32(const float* base, size_t stride,
                                               int kp, ushort_t* Dst){
  const int tid = threadIdx.x;
  const int r = tid>>2, c0 = (tid&3)*128;
  const float* s = base + (size_t)r*stride + kp + c0;
  #pragma unroll
  for (int j=0;j<16;j++){
    f4x f0 = *(const f4x*)(s + j*8);
    f4x f1 = *(const f4x*)(s + j*8 + 4);
    u8v o;
    o[0]=f2b(f0[0]); o[1]=f2b(f0[1]); o[2]=f2b(f0[2]); o[3]=f2b(f0[3]);
    o[4]=f2b(f1[0]); o[5]=f2b(f1[1]); o[6]=f2b(f1[2]); o[7]=f2b(f1[3]);
    *(u8v*)&Dst[swz(r, c0 + j*8)] = o;
  }
}
// Transposed bf16 source: Dst[col g*8+j][row k] = base[(kp+k)*stride + g*8+j]
template<bool VOL>
__device__ __forceinline__ void stage_tr_bf16(const ushort_t* base, size_t stride,
                                              int kp, ushort_t* Dst){
  const int tid = threadIdx.x;
  #pragma unroll
  for (int i=0;i<16;i++){
    int c = tid*16 + i;          // k = 2*tid + (i>>3): 2 rows/thread, coalesced-ish
    int k = c>>3, g = c&7;
    u8v v = ld8<VOL>(base + (size_t)(kp+k)*stride + g*8);
    #pragma unroll
    for (int j=0;j<8;j++) Dst[swz(g*8+j, k)] = v[j];
  }
}

// ============ MFMA bf16 GEMM: 64x64 tile, 4 waves 2x2, whole-panel K=512 ========
// One load burst (32x16B/thread) per 512-K panel -> ONE latency exposure, then
// 64 MFMA from LDS. KD=1024 phases run two panels.
template<int PHASE, int KD>
__device__ __forceinline__ void gemm_body(const Ptrs& p, int nc, int bx, int by,
                                          const float* Wp, ushort_t* Cp,
                                          ushort_t* As, ushort_t* Bs){
  const int tid = threadIdx.x;
  const int m0 = bx*64, n0 = by*64;
  const int wave = tid>>6, lane = tid&63;
  const int wm = wave&1, wn = wave>>1;
  const int quad = lane>>4, l16 = lane&15;

  f4v zz = {0.f,0.f,0.f,0.f};
  f4v acc[2][2];
  acc[0][0]=zz; acc[0][1]=zz; acc[1][0]=zz; acc[1][1]=zz;

  for (int kp=0; kp<KD; kp+=512){
    if (kp) __syncthreads();   // all waves done reading LDS before re-stage
    // ---------------- stage A panel ----------------
    if constexpr (PHASE==PH_PROJ)      stage_rows_f32(&p.x[(size_t)m0*Dd], Dd, kp, As);
    else if constexpr (PHASE==PH_H1)   stage_rows_bf16<false>(&p.kbuf[((size_t)(m0>>6)*Ss + (size_t)nc*CSc)*Dd], Dd, kp, As);
    else if constexpr (PHASE==PH_H1Q)  stage_rows_bf16<false>(&p.qbuf[((size_t)(m0>>6)*Ss + (size_t)nc*CSc)*Dd], Dd, kp, As);
    else if constexpr (PHASE==PH_PRED) stage_rows_bf16<true >(&p.a1[(size_t)m0*Hh], Hh, kp, As);
    else if constexpr (PHASE==PH_R)    stage_rows_bf16<true >(&p.d1b[(size_t)m0*Hh], Hh, kp, As);
    else if constexpr (PHASE==PH_D1)   stage_rows_bf16<true >(&p.d2b[(size_t)m0*Dd], Dd, kp, As);
    else if constexpr (PHASE==PH_OUTC) stage_rows_bf16<true >(&p.rbuf[(size_t)m0*Dd], Dd, kp, As);
    else if constexpr (PHASE==PH_UPD1) stage_tr_bf16 <true >(&p.d1b[m0], Hh, kp, As);
    else /* PH_UPD2 */                 stage_tr_bf16 <true >(&p.d2b[m0], Dd, kp, As);
    // ---------------- stage B panel ----------------
    if constexpr (PHASE==PH_PROJ)      stage_rows_f32(&Wp[(size_t)n0*Dd], Dd, kp, Bs);
    else if constexpr (PHASE==PH_OUTC) stage_rows_f32(&p.Wout[(size_t)n0*Dd], Dd, kp, Bs);
    else if constexpr (PHASE==PH_H1 || PHASE==PH_H1Q)
                                       stage_rows_bf16<true>(&p.e1[(size_t)n0*Dd], Dd, kp, Bs);
    else if constexpr (PHASE==PH_PRED || PHASE==PH_R)
                                       stage_rows_bf16<true>(&p.e2[(size_t)n0*Hh], Hh, kp, Bs);
    else if constexpr (PHASE==PH_D1)   stage_tr_bf16<true>(&p.e2[n0], Hh, kp, Bs);
    else if constexpr (PHASE==PH_UPD2) stage_tr_bf16<true>(&p.a1[n0], Hh, kp, Bs);
    else { // PH_UPD1: B[n=d][k=tok] = kbuf[cidx(tok, n0+d)] (cached, chunk-indexed)
      #pragma unroll
      for (int i=0;i<16;i++){
        int c = tid*16 + i;
        int k = c>>3, g = c&7;
        u8v v = *(const u8v*)&p.kbuf[cidx(k, n0+g*8, nc)];
        #pragma unroll
        for (int j=0;j<8;j++) Bs[swz(g*8+j, k)] = v[j];
      }
    }
    __syncthreads();
    // ---------------- MFMA over the 512-K panel ----------------
    #pragma unroll
    for (int ks=0; ks<16; ++ks){
      s8v a0 = *(const s8v*)&As[swz(wm*32 +  0 + l16, ks*32 + quad*8)];
      s8v a1f= *(const s8v*)&As[swz(wm*32 + 16 + l16, ks*32 + quad*8)];
      s8v b0 = *(const s8v*)&Bs[swz(wn*32 +  0 + l16, ks*32 + quad*8)];
      s8v b1f= *(const s8v*)&Bs[swz(wn*32 + 16 + l16, ks*32 + quad*8)];
      acc[0][0] = __builtin_amdgcn_mfma_f32_16x16x32_bf16(a0,  b0,  acc[0][0], 0,0,0);
      acc[0][1] = __builtin_amdgcn_mfma_f32_16x16x32_bf16(a0,  b1f, acc[0][1], 0,0,0);
      acc[1][0] = __builtin_amdgcn_mfma_f32_16x16x32_bf16(a1f, b0,  acc[1][0], 0,0,0);
      acc[1][1] = __builtin_amdgcn_mfma_f32_16x16x32_bf16(a1f, b1f, acc[1][1], 0,0,0);
    }
  }

  // ---------------- epilogue: D row = quad*4+r, col = l16 ----------------
  float al=0.f, lr=0.f, et=0.f;
  if constexpr (PHASE==PH_UPD1 || PHASE==PH_UPD2) {
    al = p.gates[nc]; lr = p.gates[NCn+nc]; et = p.gates[2*NCn+nc];
  }
  #pragma unroll
  for (int mf=0; mf<2; mf++) {
    #pragma unroll
    for (int nf=0; nf<2; nf++) {
      #pragma unroll
      for (int r=0; r<4; r++) {
        int m = m0 + wm*32 + mf*16 + quad*4 + r;
        int n = n0 + wn*32 + nf*16 + l16;
        float v = acc[mf][nf][r];
        if constexpr (PHASE==PH_PROJ)      Cp[(size_t)m*Dd+n] = f2b(v);
        else if constexpr (PHASE==PH_OUTC) p.out[cidx(m,n,nc)] = v;
        else if constexpr (PHASE==PH_H1) {
          vst1(&p.h1[(size_t)m*Hh+n], f2b(v));
          vst1(&p.a1[(size_t)m*Hh+n], f2b(silu_(v)));
        }
        else if constexpr (PHASE==PH_H1Q)  vst1(&p.d1b[(size_t)m*Hh+n], f2b(silu_(v)));
        else if constexpr (PHASE==PH_PRED) {
          float e = clip1_(v - b2f(p.vbuf[cidx(m,n,nc)]));
          vst1(&p.d2b[(size_t)m*Dd+n], f2b(0.03125f*e));   // scale = 2/CS
        }
        else if constexpr (PHASE==PH_R)    vst1(&p.rbuf[(size_t)m*Dd+n], f2b(v));
        else if constexpr (PHASE==PH_D1)
          vst1(&p.d1b[(size_t)m*Hh+n], f2b(v * dsilu_(b2f(vldu(&p.h1[(size_t)m*Hh+n])))));
        else if constexpr (PHASE==PH_UPD1) {
          float g = clip1_(v);
          size_t idx = (size_t)m*Dd+n;
          float m1 = et*p.M1[idx] - lr*g;        // cached: block-private state
          p.M1[idx] = m1;
          float wd = (1.0f-al)*p.Wd1[idx] + m1;
          p.Wd1[idx] = wd;
          vst1(&p.e1[idx], f2b(p.W1[idx] + wd)); // publish bf16 effective weight
        }
        else if constexpr (PHASE==PH_UPD2) {
          float g = clip1_(v);
          size_t idx = (size_t)m*Hh+n;
          float m2 = et*p.M2[idx] - lr*g;
          p.M2[idx] = m2;
          float wd = (1.0f-al)*p.Wd2[idx] + m2;
          p.Wd2[idx] = wd;
          vst1(&p.e2[idx], f2b(p.W2[idx] + wd));
        }
      }
    }
  }
}

// ---------------- projections (massively parallel, normal launch) ---------------
__global__ __launch_bounds__(256,1) void gk_proj(Ptrs p){
  __shared__ ushort_t As[64*512];
  __shared__ ushort_t Bs[64*512];
  const float* Wp = blockIdx.z==0 ? p.Wk : (blockIdx.z==1 ? p.Wv : p.Wq);
  ushort_t*    Cp = blockIdx.z==0 ? p.kbuf : (blockIdx.z==1 ? p.vbuf : p.qbuf);
  gemm_body<PH_PROJ,Dd>(p, 0, blockIdx.x, blockIdx.y, Wp, Cp, As, Bs);
}

// ---------------- atomic-free distributed grid barrier ---------------------------
__device__ __forceinline__ void gridbar(volatile unsigned* arr, volatile unsigned* rel,
                                        unsigned ep){
  __syncthreads();                      // drains this block's data stores (vmcnt 0)
  if (blockIdx.x == 0){
    int t = threadIdx.x;
    if (t > 0 && t < GRIDB){
      while (arr[t*16] < ep) __builtin_amdgcn_s_sleep(2);
    }
    __syncthreads();                    // all watchers done
    if (t == 0) rel[0] = ep;
  } else {
    if (threadIdx.x == 0){
      arr[blockIdx.x*16] = ep;
      while (rel[0] < ep) __builtin_amdgcn_s_sleep(2);
    }
  }
  __syncthreads();
  asm volatile("" ::: "memory");
}

// ---------------- persistent fused scan: 4 epochs/chunk, pipelined across chunks
// Epoch A: UPD1(nc)[128] + UPD2(nc)[128]   (also publishes e1,e2)
// Epoch B: H1Q(nc)[128] + H1(nc+1)[128]
// Epoch C: R(nc)[64]    + PRED(nc+1)[64]
// Epoch D: OUTC(nc)[64] + D1(nc+1)[128]
__global__ __launch_bounds__(256,1) void scan_k(Ptrs p, unsigned* arr, unsigned* rel){
  __shared__ ushort_t As[64*512];
  __shared__ ushort_t Bs[64*512];
  const int bid = blockIdx.x;
  unsigned ep = 0;

  // prologue: chunk 0 head of the dependency chain
  if (bid < 128) gemm_body<PH_H1,  Dd>(p, 0, bid>>4, bid&15, nullptr,nullptr, As,Bs);
  gridbar(arr, rel, ++ep);
  if (bid < 64)  gemm_body<PH_PRED,Hh>(p, 0, bid>>3, bid&7,  nullptr,nullptr, As,Bs);
  gridbar(arr, rel, ++ep);
  if (bid < 128) gemm_body<PH_D1,  Dd>(p, 0, bid>>4, bid&15, nullptr,nullptr, As,Bs);
  gridbar(arr, rel, ++ep);

  for (int nc = 0; nc < NCn; ++nc) {
    const bool more = (nc+1 < NCn);
    // ---- Epoch A: weight updates (disjoint outputs Wd1/M1/e1 vs Wd2/M2/e2) ----
    if (bid < 128) gemm_body<PH_UPD1,MROW>(p, nc, bid>>3, bid&7, nullptr,nullptr, As,Bs);
    else           gemm_body<PH_UPD2,MROW>(p, nc, (bid-128)>>4, (bid-128)&15, nullptr,nullptr, As,Bs);
    gridbar(arr, rel, ++ep);
    // ---- Epoch B: both consumers of e1_new ----
    if (bid < 128)      gemm_body<PH_H1Q,Dd>(p, nc,   bid>>4, bid&15, nullptr,nullptr, As,Bs);
    else if (more)      gemm_body<PH_H1, Dd>(p, nc+1, (bid-128)>>4, (bid-128)&15, nullptr,nullptr, As,Bs);
    gridbar(arr, rel, ++ep);
    // ---- Epoch C: both consumers of e2_new ----
    if (bid < 64)               gemm_body<PH_R,   Hh>(p, nc,   bid>>3, bid&7, nullptr,nullptr, As,Bs);
    else if (bid < 128 && more) gemm_body<PH_PRED,Hh>(p, nc+1, (bid-64)>>3, (bid-64)&7, nullptr,nullptr, As,Bs);
    gridbar(arr, rel, ++ep);
    // ---- Epoch D: output proj of nc + backward of nc+1 ----
    if (bid < 64)               gemm_body<PH_OUTC,Dd>(p, nc,   bid>>3, bid&7, nullptr,nullptr, As,Bs);
    else if (bid < 192 && more) gemm_body<PH_D1, Dd>(p, nc+1, (bid-64)>>4, (bid-64)&15, nullptr,nullptr, As,Bs);
    gridbar(arr, rel, ++ep);
  }
}

// ---------------- zero helper ----------------------------------------------------
__global__ __launch_bounds__(256)
void zero_k(float* __restrict__ ptr, int n){
  int i = blockIdx.x*256 + threadIdx.x;
  int stride = gridDim.x*256;
  for (; i < n; i += stride) ptr[i] = 0.0f;
}

// ---------------- init bf16 effective weights e1=f2b(W1), e2=f2b(W2) -------------
__global__ __launch_bounds__(256)
void einit_k(const float* __restrict__ W1, const float* __restrict__ W2,
             ushort_t* __restrict__ e1, ushort_t* __restrict__ e2){
  int i = blockIdx.x*256 + threadIdx.x;
  int stride = gridDim.x*256;
  for (; i < Hh*Dd; i += stride){
    e1[i] = f2b(W1[i]);
    e2[i] = f2b(W2[i]);
  }
}

// ---------------- halo save (last 3 rows of each chunk, pre-conv) ----------------
__global__ void halo_k(const ushort_t* __restrict__ kbuf, const ushort_t* __restrict__ vbuf,
                       const ushort_t* __restrict__ qbuf, ushort_t* __restrict__ halo){
  int bid = blockIdx.x;
  int t = bid / (NCn*Bb);
  int rem = bid % (NCn*Bb);
  int nc = rem / Bb, b = rem % Bb;
  const ushort_t* src = (t==0)?kbuf:((t==1)?vbuf:qbuf);
  ushort_t* dst = halo + (((size_t)t*NCn + nc)*Bb + b)*3*Dd;
  for (int e = threadIdx.x; e < 3*Dd; e += 256){
    int j = e / Dd, d = e % Dd;
    int s = nc*CSc + 61 + j;
    dst[e] = src[((size_t)b*Ss + s)*Dd + d];
  }
}

// ---------------- in-place causal depthwise conv (K=4) ---------------------------
__global__ void conv_k(ushort_t* __restrict__ kbuf, ushort_t* __restrict__ vbuf, ushort_t* __restrict__ qbuf,
                       const float* __restrict__ ckw, const float* __restrict__ ckb,
                       const float* __restrict__ cvw, const float* __restrict__ cvb,
                       const float* __restrict__ cqw, const float* __restrict__ cqb,
                       const ushort_t* __restrict__ halo){
  int bid = blockIdx.x;
  int t = bid / (NCn*Bb);
  int rem = bid % (NCn*Bb);
  int nc = rem / Bb, b = rem % Bb;
  ushort_t* buf = (t==0)?kbuf:((t==1)?vbuf:qbuf);
  const float* cw = (t==0)?ckw:((t==1)?cvw:cqw);
  const float* cb = (t==0)?ckb:((t==1)?cvb:cqb);
  const ushort_t* hl = halo + (((size_t)t*NCn + (nc>0?nc-1:0))*Bb + b)*3*Dd;
  for (int rep=0; rep<2; ++rep){
    int d = threadIdx.x + rep*256;
    float w0 = cw[d*4+0], w1 = cw[d*4+1], w2 = cw[d*4+2], w3 = cw[d*4+3];
    float bias = cb[d];
    float p1, p2, p3;
    if (nc == 0) { p1=p2=p3=0.0f; }
    else { p1 = b2f(hl[2*Dd+d]); p2 = b2f(hl[1*Dd+d]); p3 = b2f(hl[0*Dd+d]); }
    ushort_t* row = buf + ((size_t)b*Ss + nc*CSc)*Dd + d;
    for (int c=0;c<CSc;++c){
      float cur = b2f(row[(size_t)c*Dd]);
      float o = w3*cur + w2*p1 + w1*p2 + w0*p3 + bias;
      p3 = p2; p2 = p1; p1 = cur;
      row[(size_t)c*Dd] = f2b(o);
    }
  }
}

// ---------------- per-chunk scalar gates -----------------------------------------
__global__ __launch_bounds__(256)
void gates_k(const float* __restrict__ x,
             const float* __restrict__ wd, const float* __restrict__ bd,
             const float* __restrict__ wl, const float* __restrict__ bl,
             const float* __restrict__ we, const float* __restrict__ be,
             float* __restrict__ gates){
  int nc = blockIdx.x;
  int wave = threadIdx.x >> 6, lane = threadIdx.x & 63;
  __shared__ float red[4][3];
  float accA=0.f, accL=0.f, accE=0.f;
  float bdv = bd[0], blv = bl[0], bev = be[0];
  for (int pi = wave; pi < Bb*CSc; pi += 4) {
    int b = pi / CSc, c = pi % CSc;
    const float* xr = x + ((size_t)b*Ss + nc*CSc + c)*Dd + lane*8;
    float da=0.f, dl=0.f, de=0.f;
    #pragma unroll
    for (int u=0;u<8;++u){
      float xv = xr[u];
      int d = lane*8+u;
      da += xv*wd[d]; dl += xv*wl[d]; de += xv*we[d];
    }
    #pragma unroll
    for (int off=32; off; off>>=1){
      da += __shfl_down(da, off);
      dl += __shfl_down(dl, off);
      de += __shfl_down(de, off);
    }
    if (lane==0){
      accA += sig_(da + bdv);
      accL += sig_(dl + blv);
      accE += sig_(de + bev);
    }
  }
  if (lane==0){ red[wave][0]=accA; red[wave][1]=accL; red[wave][2]=accE; }
  __syncthreads();
  if (threadIdx.x==0){
    float a=0.f,l=0.f,e=0.f;
    for (int w=0;w<4;w++){ a+=red[w][0]; l+=red[w][1]; e+=red[w][2]; }
    gates[nc]        = a*(1.0f/512.0f);
    gates[NCn+nc]    = l*(1.0f/512.0f);
    gates[2*NCn+nc]  = e*(1.0f/512.0f);
  }
}

extern "C" void kernel_launch(void* const* d_in, const int* in_sizes, int n_in,
                              void* d_out, int out_size, void* d_ws, size_t ws_size,
                              hipStream_t stream) {
  (void)in_sizes; (void)n_in; (void)out_size;
  const float* x       = (const float*)d_in[0];
  const float* Wk      = (const float*)d_in[1];
  const float* Wv      = (const float*)d_in[2];
  const float* Wq      = (const float*)d_in[3];
  const float* Wout    = (const float*)d_in[4];
  const float* ckw     = (const float*)d_in[5];
  const float* ckb     = (const float*)d_in[6];
  const float* cvw     = (const float*)d_in[7];
  const float* cvb     = (const float*)d_in[8];
  const float* cqw     = (const float*)d_in[9];
  const float* cqb     = (const float*)d_in[10];
  const float* w_decay = (const float*)d_in[11];
  const float* b_decay = (const float*)d_in[12];
  const float* w_lr    = (const float*)d_in[13];
  const float* b_lr    = (const float*)d_in[14];
  const float* w_eta   = (const float*)d_in[15];
  const float* b_eta   = (const float*)d_in[16];
  const float* W1      = (const float*)d_in[17];
  const float* W2      = (const float*)d_in[18];

  // ---- workspace carve: fp32 state first, then bf16 buffers ----
  char* base = (char*)d_ws;
  size_t off = 0;
  auto alloc_f = [&](size_t n)->float*   { float* r=(float*)(base+off);   off += n*4; return r; };
  auto alloc_b = [&](size_t n)->ushort_t*{ ushort_t* r=(ushort_t*)(base+off); off += n*2; off=(off+15)&~15ull; return r; };

  float* Wd1  = alloc_f((size_t)Hh*Dd);
  float* M1   = alloc_f((size_t)Hh*Dd);
  float* Wd2  = alloc_f((size_t)Dd*Hh);
  float* M2   = alloc_f((size_t)Dd*Hh);
  float* gates= alloc_f(3*NCn + 4);
  float* barf = alloc_f(GRIDB*16 + 16);   // arrive slots (64B-padded) + release word

  const size_t BSD = (size_t)Bb*Ss*Dd;
  ushort_t* kbuf = alloc_b(BSD);
  ushort_t* vbuf = alloc_b(BSD);
  ushort_t* qbuf = alloc_b(BSD);
  ushort_t* halo = alloc_b((size_t)3*NCn*Bb*3*Dd);
  ushort_t* h1   = alloc_b((size_t)MROW*Hh);
  ushort_t* a1   = alloc_b((size_t)MROW*Hh);
  ushort_t* d1b  = alloc_b((size_t)MROW*Hh);
  ushort_t* d2b  = alloc_b((size_t)MROW*Dd);
  ushort_t* rbuf = alloc_b((size_t)MROW*Dd);
  ushort_t* e1   = alloc_b((size_t)Hh*Dd);
  ushort_t* e2   = alloc_b((size_t)Dd*Hh);

  if (ws_size < off) return;  // clean fail instead of fault

  // zero scan state (Wd1,M1,Wd2,M2,gates,barrier contiguous fp32 block)
  zero_k<<<1024, 256, 0, stream>>>(Wd1, 4*Hh*Dd + (3*NCn+4) + (GRIDB*16+16));
  einit_k<<<512, 256, 0, stream>>>(W1, W2, e1, e2);

  Ptrs p;
  p.x=x; p.Wk=Wk; p.Wv=Wv; p.Wq=Wq; p.Wout=Wout; p.W1=W1; p.W2=W2;
  p.kbuf=kbuf; p.vbuf=vbuf; p.qbuf=qbuf; p.rbuf=rbuf;
  p.h1=h1; p.a1=a1; p.d1b=d1b; p.d2b=d2b;
  p.e1=e1; p.e2=e2;
  p.Wd1=Wd1; p.M1=M1; p.Wd2=Wd2; p.M2=M2;
  p.gates=gates; p.out=(float*)d_out;

  unsigned* arr = (unsigned*)barf;
  unsigned* rel = (unsigned*)(barf + GRIDB*16);

  // projections: k/v/q = bf16(x) @ bf16(W^T)
  gk_proj<<<dim3(Bb*Ss/64, Dd/64, 3), 256, 0, stream>>>(p);
  halo_k<<<3*NCn*Bb, 256, 0, stream>>>(kbuf, vbuf, qbuf, halo);
  conv_k<<<3*NCn*Bb, 256, 0, stream>>>(kbuf, vbuf, qbuf, ckw, ckb, cvw, cvb, cqw, cqb, halo);
  gates_k<<<NCn, 256, 0, stream>>>(x, w_decay, b_decay, w_lr, b_lr, w_eta, b_eta, gates);

  // fused persistent chunk scan: 1 launch, 259 grid barriers, whole-panel staging
  scan_k<<<GRIDB, 256, 0, stream>>>(p, arr, rel);
}